// Round 5
// baseline (376.675 us; speedup 1.0000x reference)
//
#include <hip/hip_runtime.h>
#include <math.h>

#define BB 16
#define NL 4096
#define NH 1024
#define CL 128
#define CHH 256
#define K0 384
#define K1 256
#define CO 256
#define BN_EPS 1e-5f

typedef __attribute__((ext_vector_type(8))) short bfrag;     // 8 bf16
typedef __attribute__((ext_vector_type(4))) float f32x4;
typedef __attribute__((ext_vector_type(4))) unsigned short ushort4b;

__device__ inline unsigned short f2bf(float f) {
    unsigned int u = __builtin_bit_cast(unsigned int, f);
    u += 0x7fffu + ((u >> 16) & 1u);                 // RNE
    return (unsigned short)(u >> 16);
}
__device__ inline float bf2f(unsigned short h) {
    unsigned int u = ((unsigned int)h) << 16;
    return __builtin_bit_cast(float, u);
}

// ---------------------------------------------------------------------------
// pack candidates: cand4[b*NH+m] = (x, y, z, sum(x^2))
// ---------------------------------------------------------------------------
__global__ __launch_bounds__(256) void k_prep(const float* __restrict__ xyzh,
                                              float4* __restrict__ cand4) {
    int i = blockIdx.x * 256 + threadIdx.x;
    if (i < BB * NH) {
        float x = xyzh[3 * i], y = xyzh[3 * i + 1], z = xyzh[3 * i + 2];
        float ss = __fadd_rn(__fadd_rn(__fmul_rn(x, x), __fmul_rn(y, y)),
                             __fmul_rn(z, z));
        cand4[i] = make_float4(x, y, z, ss);
    }
}

// ---------------------------------------------------------------------------
// transpose feat_high (B, CH, NH) f32 -> fT (B, NH, CH) bf16
// ---------------------------------------------------------------------------
__global__ __launch_bounds__(256) void k_transpose_fh(const float* __restrict__ fh,
                                                      unsigned short* __restrict__ fT) {
    __shared__ float s[32][33];
    int b = blockIdx.z;
    int c0 = blockIdx.y * 32;
    int m0 = blockIdx.x * 32;
    int tx = threadIdx.x % 32, ty = threadIdx.x / 32;
    const float* src = fh + (size_t)b * CHH * NH;
    unsigned short* dst = fT + (size_t)b * NH * CHH;
#pragma unroll
    for (int j = 0; j < 4; j++)
        s[ty + 8 * j][tx] = src[(size_t)(c0 + ty + 8 * j) * NH + m0 + tx];
    __syncthreads();
    int mi = threadIdx.x >> 3;           // 0..31 point-in-tile
    int cp = threadIdx.x & 7;            // 0..7 channel-pair group
#pragma unroll
    for (int h = 0; h < 2; h++) {
        int ci = (cp + 8 * h) * 2;
        unsigned int o = (unsigned int)f2bf(s[ci][mi]) |
                         ((unsigned int)f2bf(s[ci + 1][mi]) << 16);
        *(unsigned int*)&dst[(size_t)(m0 + mi) * CHH + c0 + ci] = o;
    }
}

// ---------------------------------------------------------------------------
// 3-NN search v5: wave = segment, lane = 2 points. All 64 lanes read the SAME
// LDS address per candidate -> pure broadcast ds_read_b128, conflict-free by
// construction. Branchless top-3 on clamped d^2 (exact __f*_rn order as the
// reference), stable merge across segments. Block 256 = 4 waves; 128 pts/blk.
// ---------------------------------------------------------------------------
__global__ __launch_bounds__(256) void k_knn(const float* __restrict__ xyzl,
                                             const float4* __restrict__ cand4,
                                             int* __restrict__ idx,
                                             float* __restrict__ wgt) {
    __shared__ float4 cnd[NH];           // 16 KB
    __shared__ float tls[4][128][3];
    __shared__ int   ils[4][128][3];

    int b = blockIdx.y;
    for (int p = threadIdx.x; p < NH; p += 256)
        cnd[p] = cand4[(size_t)b * NH + p];
    __syncthreads();

    int lane = threadIdx.x & 63;
    int w = threadIdx.x >> 6;            // segment
    int nA = blockIdx.x * 128 + lane;
    int nB = nA + 64;

    const float* xa = xyzl + ((size_t)b * NL + nA) * 3;
    const float* xb = xyzl + ((size_t)b * NL + nB) * 3;
    float a0 = xa[0], a1 = xa[1], a2 = xa[2];
    float e0 = xb[0], e1 = xb[1], e2 = xb[2];
    float aa = __fadd_rn(__fadd_rn(__fmul_rn(a0, a0), __fmul_rn(a1, a1)),
                         __fmul_rn(a2, a2));
    float ae = __fadd_rn(__fadd_rn(__fmul_rn(e0, e0), __fmul_rn(e1, e1)),
                         __fmul_rn(e2, e2));

    float ta0 = INFINITY, ta1 = INFINITY, ta2 = INFINITY;
    float tb0 = INFINITY, tb1 = INFINITY, tb2 = INFINITY;
    int ia0 = 0, ia1 = 0, ia2 = 0, ib0 = 0, ib1 = 0, ib2 = 0;
    int mb = w * 256;
#pragma unroll 4
    for (int j = 0; j < 256; j++) {
        float4 c = cnd[mb + j];          // broadcast read
        int m = mb + j;
        {
            float dot = __fadd_rn(__fadd_rn(__fmul_rn(a0, c.x), __fmul_rn(a1, c.y)),
                                  __fmul_rn(a2, c.z));
            float dd = __fsub_rn(__fadd_rn(aa, c.w), __fmul_rn(2.0f, dot));
            dd = fmaxf(dd, 0.0f);
            bool c0 = dd < ta0, c1 = dd < ta1, c2 = dd < ta2;
            ta2 = c1 ? ta1 : (c2 ? dd : ta2);
            ia2 = c1 ? ia1 : (c2 ? m : ia2);
            ta1 = c0 ? ta0 : (c1 ? dd : ta1);
            ia1 = c0 ? ia0 : (c1 ? m : ia1);
            ta0 = c0 ? dd : ta0;
            ia0 = c0 ? m : ia0;
        }
        {
            float dot = __fadd_rn(__fadd_rn(__fmul_rn(e0, c.x), __fmul_rn(e1, c.y)),
                                  __fmul_rn(e2, c.z));
            float dd = __fsub_rn(__fadd_rn(ae, c.w), __fmul_rn(2.0f, dot));
            dd = fmaxf(dd, 0.0f);
            bool c0 = dd < tb0, c1 = dd < tb1, c2 = dd < tb2;
            tb2 = c1 ? tb1 : (c2 ? dd : tb2);
            ib2 = c1 ? ib1 : (c2 ? m : ib2);
            tb1 = c0 ? tb0 : (c1 ? dd : tb1);
            ib1 = c0 ? ib0 : (c1 ? m : ib1);
            tb0 = c0 ? dd : tb0;
            ib0 = c0 ? m : ib0;
        }
    }
    tls[w][lane][0] = ta0; tls[w][lane][1] = ta1; tls[w][lane][2] = ta2;
    ils[w][lane][0] = ia0; ils[w][lane][1] = ia1; ils[w][lane][2] = ia2;
    tls[w][lane + 64][0] = tb0; tls[w][lane + 64][1] = tb1; tls[w][lane + 64][2] = tb2;
    ils[w][lane + 64][0] = ib0; ils[w][lane + 64][1] = ib1; ils[w][lane + 64][2] = ib2;
    __syncthreads();

    if (threadIdx.x < 128) {
        int p = threadIdx.x;
        float u0 = tls[0][p][0], u1 = tls[0][p][1], u2 = tls[0][p][2];
        int   j0 = ils[0][p][0], j1 = ils[0][p][1], j2 = ils[0][p][2];
#pragma unroll
        for (int sg = 1; sg < 4; sg++) {
#pragma unroll
            for (int e = 0; e < 3; e++) {
                float dd = tls[sg][p][e];
                int m = ils[sg][p][e];
                bool c0 = dd < u0, c1 = dd < u1, c2 = dd < u2;
                u2 = c1 ? u1 : (c2 ? dd : u2);
                j2 = c1 ? j1 : (c2 ? m : j2);
                u1 = c0 ? u0 : (c1 ? dd : u1);
                j1 = c0 ? j0 : (c1 ? m : j1);
                u0 = c0 ? dd : u0;
                j0 = c0 ? m : j0;
            }
        }
        float d0 = sqrtf(u0), d1 = sqrtf(u1), d2 = sqrtf(u2);
        float w0 = 1.0f / fmaxf(d0, 1e-8f);
        float w1 = 1.0f / fmaxf(d1, 1e-8f);
        float w2 = 1.0f / fmaxf(d2, 1e-8f);
        float wsum = __fadd_rn(__fadd_rn(w0, w1), w2);
        w0 /= wsum; w1 /= wsum; w2 /= wsum;
        int nn = blockIdx.x * 128 + p;
        size_t base = ((size_t)b * NL + nn) * 3;
        idx[base] = j0; idx[base + 1] = j1; idx[base + 2] = j2;
        wgt[base] = w0; wgt[base + 1] = w1; wgt[base + 2] = w2;
    }
}

// ---------------------------------------------------------------------------
// interpolate -> Xb[b][n][c] bf16, c in [0, 256); fT is bf16
// ---------------------------------------------------------------------------
__global__ __launch_bounds__(256) void k_interp(const unsigned short* __restrict__ fT,
                                                const int* __restrict__ idx,
                                                const float* __restrict__ wgt,
                                                unsigned short* __restrict__ Xb) {
    int b = blockIdx.y;
    int n0 = blockIdx.x * 16;
    int c = threadIdx.x;
    const unsigned short* fTb = fT + (size_t)b * NH * CHH;
    for (int j = 0; j < 16; j++) {
        size_t base = ((size_t)b * NL + n0 + j) * 3;
        int m0 = idx[base], m1 = idx[base + 1], m2 = idx[base + 2];
        float w0 = wgt[base], w1 = wgt[base + 1], w2 = wgt[base + 2];
        float f0 = bf2f(fTb[(size_t)m0 * CHH + c]);
        float f1 = bf2f(fTb[(size_t)m1 * CHH + c]);
        float f2 = bf2f(fTb[(size_t)m2 * CHH + c]);
        float f = __fadd_rn(__fadd_rn(__fmul_rn(w0, f0), __fmul_rn(w1, f1)),
                            __fmul_rn(w2, f2));
        Xb[((size_t)b * NL + n0 + j) * K0 + c] = f2bf(f);
    }
}

// ---------------------------------------------------------------------------
// feat_low (B, CL, NL) f32 -> Xb[b][n][256 + c] bf16   (transpose-convert)
// ---------------------------------------------------------------------------
__global__ __launch_bounds__(256) void k_fl_t(const float* __restrict__ fl,
                                              unsigned short* __restrict__ Xb) {
    __shared__ unsigned short s[32][68];
    int b = blockIdx.z, c0 = blockIdx.y * 32, n0 = blockIdx.x * 64;
    int tx = threadIdx.x & 63, ty = threadIdx.x >> 6;       // 64 x 4
    const float* src = fl + ((size_t)b * CL + c0) * NL + n0;
#pragma unroll
    for (int i = 0; i < 8; i++) {
        int c = ty * 8 + i;
        s[c][tx] = f2bf(src[(size_t)c * NL + tx]);
    }
    __syncthreads();
    int n = threadIdx.x >> 2, q = threadIdx.x & 3;
    ushort4b o0, o1;
#pragma unroll
    for (int e = 0; e < 4; e++) o0[e] = s[q * 8 + e][n];
#pragma unroll
    for (int e = 0; e < 4; e++) o1[e] = s[q * 8 + 4 + e][n];
    unsigned short* dst = Xb + ((size_t)b * NL + n0 + n) * K0 + CHH + c0 + q * 8;
    *(ushort4b*)dst = o0;
    *(ushort4b*)(dst + 4) = o1;
}

// ---------------------------------------------------------------------------
// f32 -> bf16 convert for both weight matrices (one launch)
// ---------------------------------------------------------------------------
__global__ __launch_bounds__(256) void k_cvt2(const float* __restrict__ s0,
                                              unsigned short* __restrict__ d0, int n0,
                                              const float* __restrict__ s1,
                                              unsigned short* __restrict__ d1, int n1) {
    int i = blockIdx.x * 256 + threadIdx.x;
    if (i < n0) d0[i] = f2bf(s0[i]);
    else if (i < n0 + n1) d1[i - n0] = f2bf(s1[i - n0]);
}

// ---------------------------------------------------------------------------
// MFMA GEMM: Y[b][n][m] = bf16( sum_k W[m][k]*X[n][k] + bias[m] ), X n-major.
// 128x128 tile, BK=32, 4 waves, XOR-swizzled LDS, double buffer.
// Epilogue also accumulates per-m batch stats (sum, sumsq of the f32 values)
// via shfl_xor reduction + one atomicAdd per m per wave.
// ---------------------------------------------------------------------------
__device__ inline int swz(int r, int cb) {
    return r * 32 + ((cb ^ ((r >> 1) & 3)) << 3);   // short index, 16B blocks
}

template <int K>
__global__ __launch_bounds__(256) void k_gemmb(const unsigned short* __restrict__ X,
                                               const unsigned short* __restrict__ Wb,
                                               const float* __restrict__ bias,
                                               unsigned short* __restrict__ Y,
                                               float* __restrict__ psum,
                                               float* __restrict__ psq) {
    __shared__ __align__(16) unsigned short sA[2][128 * 32];
    __shared__ __align__(16) unsigned short sB[2][128 * 32];

    int b  = blockIdx.z;
    int m0 = blockIdx.y * 128;
    int n0 = blockIdx.x * 128;
    int tid = threadIdx.x;
    int lane = tid & 63;
    int wid = tid >> 6;
    int wm = wid >> 1, wn = wid & 1;

    int sr = tid >> 2;          // staging row 0..63 (and +64)
    int scb = tid & 3;          // staging 16B block
    int swA0 = swz(sr, scb), swA1 = swz(sr + 64, scb);

    const unsigned short* Wt = Wb + (size_t)m0 * K + scb * 8;
    const unsigned short* Xt = X + ((size_t)b * NL + n0) * K + scb * 8;

    f32x4 acc[4][4] = {};

    bfrag a0 = *(const bfrag*)&Wt[(size_t)sr * K];
    bfrag a1 = *(const bfrag*)&Wt[(size_t)(sr + 64) * K];
    bfrag b0 = *(const bfrag*)&Xt[(size_t)sr * K];
    bfrag b1 = *(const bfrag*)&Xt[(size_t)(sr + 64) * K];
    *(bfrag*)&sA[0][swA0] = a0;
    *(bfrag*)&sA[0][swA1] = a1;
    *(bfrag*)&sB[0][swA0] = b0;
    *(bfrag*)&sB[0][swA1] = b1;
    __syncthreads();

    const int nkt = K / 32;
    int cur = 0;
#pragma unroll 2
    for (int t = 0; t < nkt; t++) {
        bfrag na0, na1, nb0, nb1;
        bool more = (t + 1 < nkt);
        if (more) {
            int kk = (t + 1) * 32;
            na0 = *(const bfrag*)&Wt[(size_t)sr * K + kk];
            na1 = *(const bfrag*)&Wt[(size_t)(sr + 64) * K + kk];
            nb0 = *(const bfrag*)&Xt[(size_t)sr * K + kk];
            nb1 = *(const bfrag*)&Xt[(size_t)(sr + 64) * K + kk];
        }
        bfrag af[4], bf[4];
#pragma unroll
        for (int mi = 0; mi < 4; mi++) {
            int r = wm * 64 + mi * 16 + (lane & 15);
            af[mi] = *(const bfrag*)&sA[cur][swz(r, lane >> 4)];
        }
#pragma unroll
        for (int ni = 0; ni < 4; ni++) {
            int r = wn * 64 + ni * 16 + (lane & 15);
            bf[ni] = *(const bfrag*)&sB[cur][swz(r, lane >> 4)];
        }
#pragma unroll
        for (int mi = 0; mi < 4; mi++)
#pragma unroll
            for (int ni = 0; ni < 4; ni++)
                acc[mi][ni] = __builtin_amdgcn_mfma_f32_16x16x32_bf16(
                    af[mi], bf[ni], acc[mi][ni], 0, 0, 0);
        if (more) {
            *(bfrag*)&sA[cur ^ 1][swA0] = na0;
            *(bfrag*)&sA[cur ^ 1][swA1] = na1;
            *(bfrag*)&sB[cur ^ 1][swA0] = nb0;
            *(bfrag*)&sB[cur ^ 1][swA1] = nb1;
            __syncthreads();
            cur ^= 1;
        }
    }

    // C frag: col = lane&15 (n), row = (lane>>4)*4 + j (m)
    int col = lane & 15, rg = (lane >> 4) << 2;
#pragma unroll
    for (int mi = 0; mi < 4; mi++) {
        int m = m0 + wm * 64 + mi * 16 + rg;
        f32x4 bv = *(const f32x4*)&bias[m];
        f32x4 sacc = {0.f, 0.f, 0.f, 0.f}, qacc = {0.f, 0.f, 0.f, 0.f};
#pragma unroll
        for (int ni = 0; ni < 4; ni++) {
            int n = n0 + wn * 64 + ni * 16 + col;
            f32x4 c = acc[mi][ni];
            ushort4b o;
#pragma unroll
            for (int j = 0; j < 4; j++) {
                float sv = c[j] + bv[j];
                o[j] = f2bf(sv);
                sacc[j] += sv;
                qacc[j] += sv * sv;
            }
            *(ushort4b*)&Y[((size_t)b * NL + n) * CO + m] = o;
        }
#pragma unroll
        for (int j = 0; j < 4; j++) {
            float s = sacc[j], q = qacc[j];
#pragma unroll
            for (int off = 1; off < 16; off <<= 1) {
                s += __shfl_xor(s, off, 64);
                q += __shfl_xor(q, off, 64);
            }
            if (col == 0) {
                atomicAdd(&psum[m + j], s);
                atomicAdd(&psq[m + j], q);
            }
        }
    }
}

__global__ void k_fin(const float* __restrict__ psum, const float* __restrict__ psq,
                      const float* __restrict__ gamma, const float* __restrict__ beta,
                      float* __restrict__ scale, float* __restrict__ shift) {
    int c = threadIdx.x;
    float N = (float)(BB * NL);
    float mean = psum[c] / N;
    float var = psq[c] / N - mean * mean;
    float sc = gamma[c] / sqrtf(var + BN_EPS);
    scale[c] = sc;
    shift[c] = beta[c] - mean * sc;
}

// ---------------------------------------------------------------------------
// BN0 + ReLU in place on n-major bf16 y0
// ---------------------------------------------------------------------------
__global__ __launch_bounds__(256) void k_bn0(unsigned short* __restrict__ y,
                                             const float* __restrict__ scale,
                                             const float* __restrict__ shift) {
    size_t i = (size_t)blockIdx.x * 256 + threadIdx.x;      // short8 index
    unsigned short* p = y + i * 8;
    int cb = (int)(i & 31) * 8;
    bfrag v = *(bfrag*)p;
    f32x4 s0 = *(const f32x4*)&scale[cb], s1 = *(const f32x4*)&scale[cb + 4];
    f32x4 h0 = *(const f32x4*)&shift[cb], h1 = *(const f32x4*)&shift[cb + 4];
    bfrag o;
#pragma unroll
    for (int e = 0; e < 4; e++)
        o[e] = (short)f2bf(fmaxf(fmaf(s0[e], bf2f((unsigned short)v[e]), h0[e]), 0.f));
#pragma unroll
    for (int e = 0; e < 4; e++)
        o[4 + e] = (short)f2bf(fmaxf(fmaf(s1[e], bf2f((unsigned short)v[4 + e]), h1[e]), 0.f));
    *(bfrag*)p = o;
}

// ---------------------------------------------------------------------------
// final: read y1 bf16 [b][n][m], BN1+ReLU, transpose-write f32 out [b][m][n]
// ---------------------------------------------------------------------------
__global__ __launch_bounds__(256) void k_out(const unsigned short* __restrict__ y1,
                                             const float* __restrict__ scale,
                                             const float* __restrict__ shift,
                                             float* __restrict__ out) {
    __shared__ float s[64][65];
    int b = blockIdx.z, m0 = blockIdx.y * 64, n0 = blockIdx.x * 64;
    int r = threadIdx.x >> 3;            // 0..31
    int mq = (threadIdx.x & 7) * 8;      // 0..56
#pragma unroll
    for (int it = 0; it < 2; it++) {
        int row = r + it * 32;
        bfrag v = *(const bfrag*)&y1[((size_t)b * NL + n0 + row) * CO + m0 + mq];
#pragma unroll
        for (int e = 0; e < 8; e++) {
            int m = mq + e;
            float f = bf2f((unsigned short)v[e]);
            s[m][row] = fmaxf(fmaf(scale[m0 + m], f, shift[m0 + m]), 0.f);
        }
    }
    __syncthreads();
    int m = threadIdx.x >> 2, nb = (threadIdx.x & 3) * 16;
    float* orow = out + ((size_t)b * CO + m0 + m) * NL + n0 + nb;
#pragma unroll
    for (int i = 0; i < 16; i += 4) {
        float4 v = make_float4(s[m][nb + i], s[m][nb + i + 1],
                               s[m][nb + i + 2], s[m][nb + i + 3]);
        *(float4*)&orow[i] = v;
    }
}

// ---------------------------------------------------------------------------
extern "C" void kernel_launch(void* const* d_in, const int* in_sizes, int n_in,
                              void* d_out, int out_size, void* d_ws, size_t ws_size,
                              hipStream_t stream) {
    const float* xyz_low   = (const float*)d_in[0];
    const float* xyz_high  = (const float*)d_in[1];
    const float* feat_low  = (const float*)d_in[2];
    const float* feat_high = (const float*)d_in[3];
    const float* W0  = (const float*)d_in[4];
    const float* b0  = (const float*)d_in[5];
    const float* g0  = (const float*)d_in[6];
    const float* be0 = (const float*)d_in[7];
    const float* W1  = (const float*)d_in[8];
    const float* b1  = (const float*)d_in[9];
    const float* g1  = (const float*)d_in[10];
    const float* be1 = (const float*)d_in[11];
    float* out = (float*)d_out;

    char* ws = (char*)d_ws;
    // [Xb 48MB][y0 32MB][y1 32MB (fT bf16 aliases start; fT dead before gemm1)]
    unsigned short* Xb  = (unsigned short*)ws;
    unsigned short* y0  = (unsigned short*)(ws + ((size_t)48 << 20));
    unsigned short* y1  = (unsigned short*)(ws + ((size_t)80 << 20));
    unsigned short* fT  = (unsigned short*)(ws + ((size_t)80 << 20));
    char* tail          = ws + ((size_t)112 << 20);
    int*    idx   = (int*)tail;                       // 768 KB
    float*  wgt   = (float*)(tail + 786432);          // 768 KB
    float4* cand4 = (float4*)(tail + 2 * 786432);     // 256 KB
    unsigned short* Wb0 = (unsigned short*)(tail + 2 * 786432 + 262144);
    unsigned short* Wb1 = Wb0 + CO * K0;
    float* prm    = (float*)(Wb1 + CO * K1);
    float* psum0 = prm,        *psq0 = prm + 256;
    float* psum1 = prm + 512,  *psq1 = prm + 768;
    float* scale0 = prm + 1024, *shift0 = prm + 1280;
    float* scale1 = prm + 1536, *shift1 = prm + 1792;

    k_cvt2<<<(CO * (K0 + K1) + 255) / 256, 256, 0, stream>>>(
        W0, Wb0, CO * K0, W1, Wb1, CO * K1);
    k_prep<<<(BB * NH + 255) / 256, 256, 0, stream>>>(xyz_high, cand4);
    k_transpose_fh<<<dim3(NH / 32, CHH / 32, BB), 256, 0, stream>>>(feat_high, fT);
    k_knn<<<dim3(NL / 128, BB), 256, 0, stream>>>(xyz_low, cand4, idx, wgt);
    k_interp<<<dim3(NL / 16, BB), 256, 0, stream>>>(fT, idx, wgt, Xb);
    k_fl_t<<<dim3(NL / 64, CL / 32, BB), 256, 0, stream>>>(feat_low, Xb);
    hipMemsetAsync(prm, 0, 1024 * sizeof(float), stream);

    k_gemmb<K0><<<dim3(NL / 128, CO / 128, BB), 256, 0, stream>>>(
        Xb, Wb0, b0, y0, psum0, psq0);
    k_fin<<<1, 256, 0, stream>>>(psum0, psq0, g0, be0, scale0, shift0);
    k_bn0<<<(BB * NL * CO / 8) / 256, 256, 0, stream>>>(y0, scale0, shift0);
    k_gemmb<K1><<<dim3(NL / 128, CO / 128, BB), 256, 0, stream>>>(
        y0, Wb1, b1, y1, psum1, psq1);
    k_fin<<<1, 256, 0, stream>>>(psum1, psq1, g1, be1, scale1, shift1);
    k_out<<<dim3(NL / 64, CO / 64, BB), 256, 0, stream>>>(y1, scale1, shift1, out);
}

// Round 6
// 198.960 us; speedup vs baseline: 1.8932x; 1.8932x over previous
//
#include <hip/hip_runtime.h>
#include <math.h>

#define BB 16
#define NL 4096
#define NH 1024
#define CL 128
#define CHH 256
#define K0 384
#define K1 256
#define CO 256
#define BN_EPS 1e-5f

typedef __attribute__((ext_vector_type(8))) short bfrag;     // 8 bf16
typedef __attribute__((ext_vector_type(4))) float f32x4;
typedef __attribute__((ext_vector_type(4))) unsigned short ushort4b;

__device__ inline unsigned short f2bf(float f) {
    unsigned int u = __builtin_bit_cast(unsigned int, f);
    u += 0x7fffu + ((u >> 16) & 1u);                 // RNE
    return (unsigned short)(u >> 16);
}
__device__ inline float bf2f(unsigned short h) {
    unsigned int u = ((unsigned int)h) << 16;
    return __builtin_bit_cast(float, u);
}

// ---------------------------------------------------------------------------
// pack candidates: cand4[b*NH+m] = (x, y, z, sum(x^2))
// ---------------------------------------------------------------------------
__global__ __launch_bounds__(256) void k_prep(const float* __restrict__ xyzh,
                                              float4* __restrict__ cand4) {
    int i = blockIdx.x * 256 + threadIdx.x;
    if (i < BB * NH) {
        float x = xyzh[3 * i], y = xyzh[3 * i + 1], z = xyzh[3 * i + 2];
        float ss = __fadd_rn(__fadd_rn(__fmul_rn(x, x), __fmul_rn(y, y)),
                             __fmul_rn(z, z));
        cand4[i] = make_float4(x, y, z, ss);
    }
}

// ---------------------------------------------------------------------------
// transpose feat_high (B, CH, NH) f32 -> fT (B, NH, CH) bf16
// ---------------------------------------------------------------------------
__global__ __launch_bounds__(256) void k_transpose_fh(const float* __restrict__ fh,
                                                      unsigned short* __restrict__ fT) {
    __shared__ float s[32][33];
    int b = blockIdx.z;
    int c0 = blockIdx.y * 32;
    int m0 = blockIdx.x * 32;
    int tx = threadIdx.x % 32, ty = threadIdx.x / 32;
    const float* src = fh + (size_t)b * CHH * NH;
    unsigned short* dst = fT + (size_t)b * NH * CHH;
#pragma unroll
    for (int j = 0; j < 4; j++)
        s[ty + 8 * j][tx] = src[(size_t)(c0 + ty + 8 * j) * NH + m0 + tx];
    __syncthreads();
    int mi = threadIdx.x >> 3;           // 0..31 point-in-tile
    int cp = threadIdx.x & 7;            // 0..7 channel-pair group
#pragma unroll
    for (int h = 0; h < 2; h++) {
        int ci = (cp + 8 * h) * 2;
        unsigned int o = (unsigned int)f2bf(s[ci][mi]) |
                         ((unsigned int)f2bf(s[ci + 1][mi]) << 16);
        *(unsigned int*)&dst[(size_t)(m0 + mi) * CHH + c0 + ci] = o;
    }
}

// ---------------------------------------------------------------------------
// 3-NN search v5: wave = segment, lane = 2 points. All 64 lanes read the SAME
// LDS address per candidate -> pure broadcast ds_read_b128, conflict-free by
// construction. Branchless top-3 on clamped d^2 (exact __f*_rn order as the
// reference), stable merge across segments. Block 256 = 4 waves; 128 pts/blk.
// ---------------------------------------------------------------------------
__global__ __launch_bounds__(256) void k_knn(const float* __restrict__ xyzl,
                                             const float4* __restrict__ cand4,
                                             int* __restrict__ idx,
                                             float* __restrict__ wgt) {
    __shared__ float4 cnd[NH];           // 16 KB
    __shared__ float tls[4][128][3];
    __shared__ int   ils[4][128][3];

    int b = blockIdx.y;
    for (int p = threadIdx.x; p < NH; p += 256)
        cnd[p] = cand4[(size_t)b * NH + p];
    __syncthreads();

    int lane = threadIdx.x & 63;
    int w = threadIdx.x >> 6;            // segment
    int nA = blockIdx.x * 128 + lane;
    int nB = nA + 64;

    const float* xa = xyzl + ((size_t)b * NL + nA) * 3;
    const float* xb = xyzl + ((size_t)b * NL + nB) * 3;
    float a0 = xa[0], a1 = xa[1], a2 = xa[2];
    float e0 = xb[0], e1 = xb[1], e2 = xb[2];
    float aa = __fadd_rn(__fadd_rn(__fmul_rn(a0, a0), __fmul_rn(a1, a1)),
                         __fmul_rn(a2, a2));
    float ae = __fadd_rn(__fadd_rn(__fmul_rn(e0, e0), __fmul_rn(e1, e1)),
                         __fmul_rn(e2, e2));

    float ta0 = INFINITY, ta1 = INFINITY, ta2 = INFINITY;
    float tb0 = INFINITY, tb1 = INFINITY, tb2 = INFINITY;
    int ia0 = 0, ia1 = 0, ia2 = 0, ib0 = 0, ib1 = 0, ib2 = 0;
    int mb = w * 256;
#pragma unroll 4
    for (int j = 0; j < 256; j++) {
        float4 c = cnd[mb + j];          // broadcast read
        int m = mb + j;
        {
            float dot = __fadd_rn(__fadd_rn(__fmul_rn(a0, c.x), __fmul_rn(a1, c.y)),
                                  __fmul_rn(a2, c.z));
            float dd = __fsub_rn(__fadd_rn(aa, c.w), __fmul_rn(2.0f, dot));
            dd = fmaxf(dd, 0.0f);
            bool c0 = dd < ta0, c1 = dd < ta1, c2 = dd < ta2;
            ta2 = c1 ? ta1 : (c2 ? dd : ta2);
            ia2 = c1 ? ia1 : (c2 ? m : ia2);
            ta1 = c0 ? ta0 : (c1 ? dd : ta1);
            ia1 = c0 ? ia0 : (c1 ? m : ia1);
            ta0 = c0 ? dd : ta0;
            ia0 = c0 ? m : ia0;
        }
        {
            float dot = __fadd_rn(__fadd_rn(__fmul_rn(e0, c.x), __fmul_rn(e1, c.y)),
                                  __fmul_rn(e2, c.z));
            float dd = __fsub_rn(__fadd_rn(ae, c.w), __fmul_rn(2.0f, dot));
            dd = fmaxf(dd, 0.0f);
            bool c0 = dd < tb0, c1 = dd < tb1, c2 = dd < tb2;
            tb2 = c1 ? tb1 : (c2 ? dd : tb2);
            ib2 = c1 ? ib1 : (c2 ? m : ib2);
            tb1 = c0 ? tb0 : (c1 ? dd : tb1);
            ib1 = c0 ? ib0 : (c1 ? m : ib1);
            tb0 = c0 ? dd : tb0;
            ib0 = c0 ? m : ib0;
        }
    }
    tls[w][lane][0] = ta0; tls[w][lane][1] = ta1; tls[w][lane][2] = ta2;
    ils[w][lane][0] = ia0; ils[w][lane][1] = ia1; ils[w][lane][2] = ia2;
    tls[w][lane + 64][0] = tb0; tls[w][lane + 64][1] = tb1; tls[w][lane + 64][2] = tb2;
    ils[w][lane + 64][0] = ib0; ils[w][lane + 64][1] = ib1; ils[w][lane + 64][2] = ib2;
    __syncthreads();

    if (threadIdx.x < 128) {
        int p = threadIdx.x;
        float u0 = tls[0][p][0], u1 = tls[0][p][1], u2 = tls[0][p][2];
        int   j0 = ils[0][p][0], j1 = ils[0][p][1], j2 = ils[0][p][2];
#pragma unroll
        for (int sg = 1; sg < 4; sg++) {
#pragma unroll
            for (int e = 0; e < 3; e++) {
                float dd = tls[sg][p][e];
                int m = ils[sg][p][e];
                bool c0 = dd < u0, c1 = dd < u1, c2 = dd < u2;
                u2 = c1 ? u1 : (c2 ? dd : u2);
                j2 = c1 ? j1 : (c2 ? m : j2);
                u1 = c0 ? u0 : (c1 ? dd : u1);
                j1 = c0 ? j0 : (c1 ? m : j1);
                u0 = c0 ? dd : u0;
                j0 = c0 ? m : j0;
            }
        }
        float d0 = sqrtf(u0), d1 = sqrtf(u1), d2 = sqrtf(u2);
        float w0 = 1.0f / fmaxf(d0, 1e-8f);
        float w1 = 1.0f / fmaxf(d1, 1e-8f);
        float w2 = 1.0f / fmaxf(d2, 1e-8f);
        float wsum = __fadd_rn(__fadd_rn(w0, w1), w2);
        w0 /= wsum; w1 /= wsum; w2 /= wsum;
        int nn = blockIdx.x * 128 + p;
        size_t base = ((size_t)b * NL + nn) * 3;
        idx[base] = j0; idx[base + 1] = j1; idx[base + 2] = j2;
        wgt[base] = w0; wgt[base + 1] = w1; wgt[base + 2] = w2;
    }
}

// ---------------------------------------------------------------------------
// interpolate -> Xb[b][n][c] bf16, c in [0, 256); fT is bf16
// ---------------------------------------------------------------------------
__global__ __launch_bounds__(256) void k_interp(const unsigned short* __restrict__ fT,
                                                const int* __restrict__ idx,
                                                const float* __restrict__ wgt,
                                                unsigned short* __restrict__ Xb) {
    int b = blockIdx.y;
    int n0 = blockIdx.x * 16;
    int c = threadIdx.x;
    const unsigned short* fTb = fT + (size_t)b * NH * CHH;
    for (int j = 0; j < 16; j++) {
        size_t base = ((size_t)b * NL + n0 + j) * 3;
        int m0 = idx[base], m1 = idx[base + 1], m2 = idx[base + 2];
        float w0 = wgt[base], w1 = wgt[base + 1], w2 = wgt[base + 2];
        float f0 = bf2f(fTb[(size_t)m0 * CHH + c]);
        float f1 = bf2f(fTb[(size_t)m1 * CHH + c]);
        float f2 = bf2f(fTb[(size_t)m2 * CHH + c]);
        float f = __fadd_rn(__fadd_rn(__fmul_rn(w0, f0), __fmul_rn(w1, f1)),
                            __fmul_rn(w2, f2));
        Xb[((size_t)b * NL + n0 + j) * K0 + c] = f2bf(f);
    }
}

// ---------------------------------------------------------------------------
// feat_low (B, CL, NL) f32 -> Xb[b][n][256 + c] bf16   (transpose-convert)
// ---------------------------------------------------------------------------
__global__ __launch_bounds__(256) void k_fl_t(const float* __restrict__ fl,
                                              unsigned short* __restrict__ Xb) {
    __shared__ unsigned short s[32][68];
    int b = blockIdx.z, c0 = blockIdx.y * 32, n0 = blockIdx.x * 64;
    int tx = threadIdx.x & 63, ty = threadIdx.x >> 6;       // 64 x 4
    const float* src = fl + ((size_t)b * CL + c0) * NL + n0;
#pragma unroll
    for (int i = 0; i < 8; i++) {
        int c = ty * 8 + i;
        s[c][tx] = f2bf(src[(size_t)c * NL + tx]);
    }
    __syncthreads();
    int n = threadIdx.x >> 2, q = threadIdx.x & 3;
    ushort4b o0, o1;
#pragma unroll
    for (int e = 0; e < 4; e++) o0[e] = s[q * 8 + e][n];
#pragma unroll
    for (int e = 0; e < 4; e++) o1[e] = s[q * 8 + 4 + e][n];
    unsigned short* dst = Xb + ((size_t)b * NL + n0 + n) * K0 + CHH + c0 + q * 8;
    *(ushort4b*)dst = o0;
    *(ushort4b*)(dst + 4) = o1;
}

// ---------------------------------------------------------------------------
// f32 -> bf16 convert for both weight matrices (one launch)
// ---------------------------------------------------------------------------
__global__ __launch_bounds__(256) void k_cvt2(const float* __restrict__ s0,
                                              unsigned short* __restrict__ d0, int n0,
                                              const float* __restrict__ s1,
                                              unsigned short* __restrict__ d1, int n1) {
    int i = blockIdx.x * 256 + threadIdx.x;
    if (i < n0) d0[i] = f2bf(s0[i]);
    else if (i < n0 + n1) d1[i - n0] = f2bf(s1[i - n0]);
}

// ---------------------------------------------------------------------------
// MFMA GEMM: Y[b][n][m] = bf16( sum_k W[m][k]*X[n][k] + bias[m] ), X n-major.
// 128x128 tile, BK=32, 4 waves, XOR-swizzled LDS, double buffer.
// (Stats fusion reverted: 262K hot-line atomics serialized ~90us/launch.)
// ---------------------------------------------------------------------------
__device__ inline int swz(int r, int cb) {
    return r * 32 + ((cb ^ ((r >> 1) & 3)) << 3);   // short index, 16B blocks
}

template <int K>
__global__ __launch_bounds__(256) void k_gemmb(const unsigned short* __restrict__ X,
                                               const unsigned short* __restrict__ Wb,
                                               const float* __restrict__ bias,
                                               unsigned short* __restrict__ Y) {
    __shared__ __align__(16) unsigned short sA[2][128 * 32];
    __shared__ __align__(16) unsigned short sB[2][128 * 32];

    int b  = blockIdx.z;
    int m0 = blockIdx.y * 128;
    int n0 = blockIdx.x * 128;
    int tid = threadIdx.x;
    int lane = tid & 63;
    int wid = tid >> 6;
    int wm = wid >> 1, wn = wid & 1;

    int sr = tid >> 2;          // staging row 0..63 (and +64)
    int scb = tid & 3;          // staging 16B block
    int swA0 = swz(sr, scb), swA1 = swz(sr + 64, scb);

    const unsigned short* Wt = Wb + (size_t)m0 * K + scb * 8;
    const unsigned short* Xt = X + ((size_t)b * NL + n0) * K + scb * 8;

    f32x4 acc[4][4] = {};

    bfrag a0 = *(const bfrag*)&Wt[(size_t)sr * K];
    bfrag a1 = *(const bfrag*)&Wt[(size_t)(sr + 64) * K];
    bfrag b0 = *(const bfrag*)&Xt[(size_t)sr * K];
    bfrag b1 = *(const bfrag*)&Xt[(size_t)(sr + 64) * K];
    *(bfrag*)&sA[0][swA0] = a0;
    *(bfrag*)&sA[0][swA1] = a1;
    *(bfrag*)&sB[0][swA0] = b0;
    *(bfrag*)&sB[0][swA1] = b1;
    __syncthreads();

    const int nkt = K / 32;
    int cur = 0;
#pragma unroll 2
    for (int t = 0; t < nkt; t++) {
        bfrag na0, na1, nb0, nb1;
        bool more = (t + 1 < nkt);
        if (more) {
            int kk = (t + 1) * 32;
            na0 = *(const bfrag*)&Wt[(size_t)sr * K + kk];
            na1 = *(const bfrag*)&Wt[(size_t)(sr + 64) * K + kk];
            nb0 = *(const bfrag*)&Xt[(size_t)sr * K + kk];
            nb1 = *(const bfrag*)&Xt[(size_t)(sr + 64) * K + kk];
        }
        bfrag af[4], bf[4];
#pragma unroll
        for (int mi = 0; mi < 4; mi++) {
            int r = wm * 64 + mi * 16 + (lane & 15);
            af[mi] = *(const bfrag*)&sA[cur][swz(r, lane >> 4)];
        }
#pragma unroll
        for (int ni = 0; ni < 4; ni++) {
            int r = wn * 64 + ni * 16 + (lane & 15);
            bf[ni] = *(const bfrag*)&sB[cur][swz(r, lane >> 4)];
        }
#pragma unroll
        for (int mi = 0; mi < 4; mi++)
#pragma unroll
            for (int ni = 0; ni < 4; ni++)
                acc[mi][ni] = __builtin_amdgcn_mfma_f32_16x16x32_bf16(
                    af[mi], bf[ni], acc[mi][ni], 0, 0, 0);
        if (more) {
            *(bfrag*)&sA[cur ^ 1][swA0] = na0;
            *(bfrag*)&sA[cur ^ 1][swA1] = na1;
            *(bfrag*)&sB[cur ^ 1][swA0] = nb0;
            *(bfrag*)&sB[cur ^ 1][swA1] = nb1;
            __syncthreads();
            cur ^= 1;
        }
    }

    // C frag: col = lane&15 (n), row = (lane>>4)*4 + j (m)
    int col = lane & 15, rg = (lane >> 4) << 2;
#pragma unroll
    for (int mi = 0; mi < 4; mi++) {
        int m = m0 + wm * 64 + mi * 16 + rg;
        f32x4 bv = *(const f32x4*)&bias[m];
#pragma unroll
        for (int ni = 0; ni < 4; ni++) {
            int n = n0 + wn * 64 + ni * 16 + col;
            f32x4 c = acc[mi][ni];
            ushort4b o;
            o[0] = f2bf(c[0] + bv[0]); o[1] = f2bf(c[1] + bv[1]);
            o[2] = f2bf(c[2] + bv[2]); o[3] = f2bf(c[3] + bv[3]);
            *(ushort4b*)&Y[((size_t)b * NL + n) * CO + m] = o;
        }
    }
}

// ---------------------------------------------------------------------------
// stats over n-major bf16 (65536 rows x 256 ch) -> atomic partial sums
// (block-level reduction first: 512 atomics total per pass)
// ---------------------------------------------------------------------------
__global__ __launch_bounds__(256) void k_stats(const unsigned short* __restrict__ y,
                                               float* __restrict__ psum,
                                               float* __restrict__ psq) {
    int r0 = blockIdx.x * 256;
    int lane = threadIdx.x & 63, wid = threadIdx.x >> 6;
    float s[4] = {0, 0, 0, 0}, q[4] = {0, 0, 0, 0};
    for (int j = 0; j < 64; j++) {
        int r = r0 + wid * 64 + j;
        ushort4b v = *(const ushort4b*)&y[(size_t)r * CO + lane * 4];
#pragma unroll
        for (int e = 0; e < 4; e++) {
            float f = bf2f(v[e]);
            s[e] += f; q[e] += f * f;
        }
    }
    __shared__ float ls[4][256], lq[4][256];
#pragma unroll
    for (int e = 0; e < 4; e++) {
        ls[wid][lane * 4 + e] = s[e];
        lq[wid][lane * 4 + e] = q[e];
    }
    __syncthreads();
    int c = threadIdx.x;
    float S = ls[0][c] + ls[1][c] + ls[2][c] + ls[3][c];
    float Q = lq[0][c] + lq[1][c] + lq[2][c] + lq[3][c];
    atomicAdd(&psum[c], S);
    atomicAdd(&psq[c], Q);
}

__global__ void k_fin(const float* __restrict__ psum, const float* __restrict__ psq,
                      const float* __restrict__ gamma, const float* __restrict__ beta,
                      float* __restrict__ scale, float* __restrict__ shift) {
    int c = threadIdx.x;
    float N = (float)(BB * NL);
    float mean = psum[c] / N;
    float var = psq[c] / N - mean * mean;
    float sc = gamma[c] / sqrtf(var + BN_EPS);
    scale[c] = sc;
    shift[c] = beta[c] - mean * sc;
}

// ---------------------------------------------------------------------------
// BN0 + ReLU in place on n-major bf16 y0
// ---------------------------------------------------------------------------
__global__ __launch_bounds__(256) void k_bn0(unsigned short* __restrict__ y,
                                             const float* __restrict__ scale,
                                             const float* __restrict__ shift) {
    size_t i = (size_t)blockIdx.x * 256 + threadIdx.x;      // short8 index
    unsigned short* p = y + i * 8;
    int cb = (int)(i & 31) * 8;
    bfrag v = *(bfrag*)p;
    f32x4 s0 = *(const f32x4*)&scale[cb], s1 = *(const f32x4*)&scale[cb + 4];
    f32x4 h0 = *(const f32x4*)&shift[cb], h1 = *(const f32x4*)&shift[cb + 4];
    bfrag o;
#pragma unroll
    for (int e = 0; e < 4; e++)
        o[e] = (short)f2bf(fmaxf(fmaf(s0[e], bf2f((unsigned short)v[e]), h0[e]), 0.f));
#pragma unroll
    for (int e = 0; e < 4; e++)
        o[4 + e] = (short)f2bf(fmaxf(fmaf(s1[e], bf2f((unsigned short)v[4 + e]), h1[e]), 0.f));
    *(bfrag*)p = o;
}

// ---------------------------------------------------------------------------
// final: read y1 bf16 [b][n][m], BN1+ReLU, transpose-write f32 out [b][m][n]
// ---------------------------------------------------------------------------
__global__ __launch_bounds__(256) void k_out(const unsigned short* __restrict__ y1,
                                             const float* __restrict__ scale,
                                             const float* __restrict__ shift,
                                             float* __restrict__ out) {
    __shared__ float s[64][65];
    int b = blockIdx.z, m0 = blockIdx.y * 64, n0 = blockIdx.x * 64;
    int r = threadIdx.x >> 3;            // 0..31
    int mq = (threadIdx.x & 7) * 8;      // 0..56
#pragma unroll
    for (int it = 0; it < 2; it++) {
        int row = r + it * 32;
        bfrag v = *(const bfrag*)&y1[((size_t)b * NL + n0 + row) * CO + m0 + mq];
#pragma unroll
        for (int e = 0; e < 8; e++) {
            int m = mq + e;
            float f = bf2f((unsigned short)v[e]);
            s[m][row] = fmaxf(fmaf(scale[m0 + m], f, shift[m0 + m]), 0.f);
        }
    }
    __syncthreads();
    int m = threadIdx.x >> 2, nb = (threadIdx.x & 3) * 16;
    float* orow = out + ((size_t)b * CO + m0 + m) * NL + n0 + nb;
#pragma unroll
    for (int i = 0; i < 16; i += 4) {
        float4 v = make_float4(s[m][nb + i], s[m][nb + i + 1],
                               s[m][nb + i + 2], s[m][nb + i + 3]);
        *(float4*)&orow[i] = v;
    }
}

// ---------------------------------------------------------------------------
extern "C" void kernel_launch(void* const* d_in, const int* in_sizes, int n_in,
                              void* d_out, int out_size, void* d_ws, size_t ws_size,
                              hipStream_t stream) {
    const float* xyz_low   = (const float*)d_in[0];
    const float* xyz_high  = (const float*)d_in[1];
    const float* feat_low  = (const float*)d_in[2];
    const float* feat_high = (const float*)d_in[3];
    const float* W0  = (const float*)d_in[4];
    const float* b0  = (const float*)d_in[5];
    const float* g0  = (const float*)d_in[6];
    const float* be0 = (const float*)d_in[7];
    const float* W1  = (const float*)d_in[8];
    const float* b1  = (const float*)d_in[9];
    const float* g1  = (const float*)d_in[10];
    const float* be1 = (const float*)d_in[11];
    float* out = (float*)d_out;

    char* ws = (char*)d_ws;
    // [Xb 48MB][y0 32MB][y1 32MB (fT bf16 aliases start; fT dead before gemm1)]
    unsigned short* Xb  = (unsigned short*)ws;
    unsigned short* y0  = (unsigned short*)(ws + ((size_t)48 << 20));
    unsigned short* y1  = (unsigned short*)(ws + ((size_t)80 << 20));
    unsigned short* fT  = (unsigned short*)(ws + ((size_t)80 << 20));
    char* tail          = ws + ((size_t)112 << 20);
    int*    idx   = (int*)tail;                       // 768 KB
    float*  wgt   = (float*)(tail + 786432);          // 768 KB
    float4* cand4 = (float4*)(tail + 2 * 786432);     // 256 KB
    unsigned short* Wb0 = (unsigned short*)(tail + 2 * 786432 + 262144);
    unsigned short* Wb1 = Wb0 + CO * K0;
    float* prm    = (float*)(Wb1 + CO * K1);
    float* psum0 = prm,        *psq0 = prm + 256;
    float* psum1 = prm + 512,  *psq1 = prm + 768;
    float* scale0 = prm + 1024, *shift0 = prm + 1280;
    float* scale1 = prm + 1536, *shift1 = prm + 1792;

    k_cvt2<<<(CO * (K0 + K1) + 255) / 256, 256, 0, stream>>>(
        W0, Wb0, CO * K0, W1, Wb1, CO * K1);
    k_prep<<<(BB * NH + 255) / 256, 256, 0, stream>>>(xyz_high, cand4);
    k_transpose_fh<<<dim3(NH / 32, CHH / 32, BB), 256, 0, stream>>>(feat_high, fT);
    k_knn<<<dim3(NL / 128, BB), 256, 0, stream>>>(xyz_low, cand4, idx, wgt);
    k_interp<<<dim3(NL / 16, BB), 256, 0, stream>>>(fT, idx, wgt, Xb);
    k_fl_t<<<dim3(NL / 64, CL / 32, BB), 256, 0, stream>>>(feat_low, Xb);
    hipMemsetAsync(prm, 0, 1024 * sizeof(float), stream);

    k_gemmb<K0><<<dim3(NL / 128, CO / 128, BB), 256, 0, stream>>>(Xb, Wb0, b0, y0);
    k_stats<<<256, 256, 0, stream>>>(y0, psum0, psq0);
    k_fin<<<1, 256, 0, stream>>>(psum0, psq0, g0, be0, scale0, shift0);
    k_bn0<<<(BB * NL * CO / 8) / 256, 256, 0, stream>>>(y0, scale0, shift0);
    k_gemmb<K1><<<dim3(NL / 128, CO / 128, BB), 256, 0, stream>>>(y0, Wb1, b1, y1);
    k_stats<<<256, 256, 0, stream>>>(y1, psum1, psq1);
    k_fin<<<1, 256, 0, stream>>>(psum1, psq1, g1, be1, scale1, shift1);
    k_out<<<dim3(NL / 64, CO / 64, BB), 256, 0, stream>>>(y1, scale1, shift1, out);
}

// Round 7
// 198.606 us; speedup vs baseline: 1.8966x; 1.0018x over previous
//
#include <hip/hip_runtime.h>
#include <math.h>

#define BB 16
#define NL 4096
#define NH 1024
#define CL 128
#define CHH 256
#define K0 384
#define K1 256
#define CO 256
#define BN_EPS 1e-5f

typedef __attribute__((ext_vector_type(8))) short bfrag;     // 8 bf16
typedef __attribute__((ext_vector_type(4))) float f32x4;
typedef __attribute__((ext_vector_type(4))) unsigned short ushort4b;

__device__ inline unsigned short f2bf(float f) {
    unsigned int u = __builtin_bit_cast(unsigned int, f);
    u += 0x7fffu + ((u >> 16) & 1u);                 // RNE
    return (unsigned short)(u >> 16);
}
__device__ inline float bf2f(unsigned short h) {
    unsigned int u = ((unsigned int)h) << 16;
    return __builtin_bit_cast(float, u);
}

// ---------------------------------------------------------------------------
// pack candidates: cand4[b*NH+m] = (x, y, z, sum(x^2))
// ---------------------------------------------------------------------------
__global__ __launch_bounds__(256) void k_prep(const float* __restrict__ xyzh,
                                              float4* __restrict__ cand4) {
    int i = blockIdx.x * 256 + threadIdx.x;
    if (i < BB * NH) {
        float x = xyzh[3 * i], y = xyzh[3 * i + 1], z = xyzh[3 * i + 2];
        float ss = __fadd_rn(__fadd_rn(__fmul_rn(x, x), __fmul_rn(y, y)),
                             __fmul_rn(z, z));
        cand4[i] = make_float4(x, y, z, ss);
    }
}

// ---------------------------------------------------------------------------
// transpose feat_high (B, CH, NH) f32 -> fT (B, NH, CH) bf16
// ---------------------------------------------------------------------------
__global__ __launch_bounds__(256) void k_transpose_fh(const float* __restrict__ fh,
                                                      unsigned short* __restrict__ fT) {
    __shared__ float s[32][33];
    int b = blockIdx.z;
    int c0 = blockIdx.y * 32;
    int m0 = blockIdx.x * 32;
    int tx = threadIdx.x % 32, ty = threadIdx.x / 32;
    const float* src = fh + (size_t)b * CHH * NH;
    unsigned short* dst = fT + (size_t)b * NH * CHH;
#pragma unroll
    for (int j = 0; j < 4; j++)
        s[ty + 8 * j][tx] = src[(size_t)(c0 + ty + 8 * j) * NH + m0 + tx];
    __syncthreads();
    int mi = threadIdx.x >> 3;           // 0..31 point-in-tile
    int cp = threadIdx.x & 7;            // 0..7 channel-pair group
#pragma unroll
    for (int h = 0; h < 2; h++) {
        int ci = (cp + 8 * h) * 2;
        unsigned int o = (unsigned int)f2bf(s[ci][mi]) |
                         ((unsigned int)f2bf(s[ci + 1][mi]) << 16);
        *(unsigned int*)&dst[(size_t)(m0 + mi) * CHH + c0 + ci] = o;
    }
}

// ---------------------------------------------------------------------------
// 3-NN search v6: wave = segment (broadcast LDS reads, conflict-free),
// lane = 1 point, 4 blocks/CU. Top-3 values via min/med3 (bit-identical to
// the cndmask cascade; exact __f*_rn distance order as reference); indices
// via cmp+cndmask. Stable merge across segments unchanged.
// Block 256 = 4 waves; 64 pts/block. Grid: (NL/64, B) = 1024 blocks.
// ---------------------------------------------------------------------------
__global__ __launch_bounds__(256) void k_knn(const float* __restrict__ xyzl,
                                             const float4* __restrict__ cand4,
                                             int* __restrict__ idx,
                                             float* __restrict__ wgt) {
    __shared__ float4 cnd[NH];           // 16 KB
    __shared__ float tls[4][64][3];
    __shared__ int   ils[4][64][3];

    int b = blockIdx.y;
    for (int p = threadIdx.x; p < NH; p += 256)
        cnd[p] = cand4[(size_t)b * NH + p];
    __syncthreads();

    int lane = threadIdx.x & 63;
    int w = threadIdx.x >> 6;            // segment
    int n = blockIdx.x * 64 + lane;

    const float* xl = xyzl + ((size_t)b * NL + n) * 3;
    float l0 = xl[0], l1 = xl[1], l2 = xl[2];
    float a = __fadd_rn(__fadd_rn(__fmul_rn(l0, l0), __fmul_rn(l1, l1)),
                        __fmul_rn(l2, l2));

    float t0 = INFINITY, t1 = INFINITY, t2 = INFINITY;
    int i0 = 0, i1 = 0, i2 = 0;
    int mb = w * 256;
#pragma unroll 4
    for (int j = 0; j < 256; j++) {
        float4 c = cnd[mb + j];          // broadcast read
        int m = mb + j;
        float dot = __fadd_rn(__fadd_rn(__fmul_rn(l0, c.x), __fmul_rn(l1, c.y)),
                              __fmul_rn(l2, c.z));
        float dd = __fsub_rn(__fadd_rn(a, c.w), __fmul_rn(2.0f, dot));
        dd = fmaxf(dd, 0.0f);
        bool c0 = dd < t0, c1 = dd < t1, c2 = dd < t2;
        // values: sorted-insert == min/med3 (bit-identical incl. ties)
        float nt0 = fminf(dd, t0);
        float nt1 = __builtin_amdgcn_fmed3f(dd, t0, t1);
        float nt2 = __builtin_amdgcn_fmed3f(dd, t1, t2);
        i2 = c1 ? i1 : (c2 ? m : i2);
        i1 = c0 ? i0 : (c1 ? m : i1);
        i0 = c0 ? m : i0;
        t0 = nt0; t1 = nt1; t2 = nt2;
    }
    tls[w][lane][0] = t0; tls[w][lane][1] = t1; tls[w][lane][2] = t2;
    ils[w][lane][0] = i0; ils[w][lane][1] = i1; ils[w][lane][2] = i2;
    __syncthreads();

    if (threadIdx.x < 64) {
        int p = threadIdx.x;
        float u0 = tls[0][p][0], u1 = tls[0][p][1], u2 = tls[0][p][2];
        int   j0 = ils[0][p][0], j1 = ils[0][p][1], j2 = ils[0][p][2];
#pragma unroll
        for (int sg = 1; sg < 4; sg++) {
#pragma unroll
            for (int e = 0; e < 3; e++) {
                float dd = tls[sg][p][e];
                int m = ils[sg][p][e];
                bool c0 = dd < u0, c1 = dd < u1, c2 = dd < u2;
                u2 = c1 ? u1 : (c2 ? dd : u2);
                j2 = c1 ? j1 : (c2 ? m : j2);
                u1 = c0 ? u0 : (c1 ? dd : u1);
                j1 = c0 ? j0 : (c1 ? m : j1);
                u0 = c0 ? dd : u0;
                j0 = c0 ? m : j0;
            }
        }
        float d0 = sqrtf(u0), d1 = sqrtf(u1), d2 = sqrtf(u2);
        float w0 = 1.0f / fmaxf(d0, 1e-8f);
        float w1 = 1.0f / fmaxf(d1, 1e-8f);
        float w2 = 1.0f / fmaxf(d2, 1e-8f);
        float wsum = __fadd_rn(__fadd_rn(w0, w1), w2);
        w0 /= wsum; w1 /= wsum; w2 /= wsum;
        int nn = blockIdx.x * 64 + p;
        size_t base = ((size_t)b * NL + nn) * 3;
        idx[base] = j0; idx[base + 1] = j1; idx[base + 2] = j2;
        wgt[base] = w0; wgt[base + 1] = w1; wgt[base + 2] = w2;
    }
}

// ---------------------------------------------------------------------------
// interpolate -> Xb[b][n][c] bf16, c in [0, 256); fT is bf16
// ---------------------------------------------------------------------------
__global__ __launch_bounds__(256) void k_interp(const unsigned short* __restrict__ fT,
                                                const int* __restrict__ idx,
                                                const float* __restrict__ wgt,
                                                unsigned short* __restrict__ Xb) {
    int b = blockIdx.y;
    int n0 = blockIdx.x * 16;
    int c = threadIdx.x;
    const unsigned short* fTb = fT + (size_t)b * NH * CHH;
    for (int j = 0; j < 16; j++) {
        size_t base = ((size_t)b * NL + n0 + j) * 3;
        int m0 = idx[base], m1 = idx[base + 1], m2 = idx[base + 2];
        float w0 = wgt[base], w1 = wgt[base + 1], w2 = wgt[base + 2];
        float f0 = bf2f(fTb[(size_t)m0 * CHH + c]);
        float f1 = bf2f(fTb[(size_t)m1 * CHH + c]);
        float f2 = bf2f(fTb[(size_t)m2 * CHH + c]);
        float f = __fadd_rn(__fadd_rn(__fmul_rn(w0, f0), __fmul_rn(w1, f1)),
                            __fmul_rn(w2, f2));
        Xb[((size_t)b * NL + n0 + j) * K0 + c] = f2bf(f);
    }
}

// ---------------------------------------------------------------------------
// feat_low (B, CL, NL) f32 -> Xb[b][n][256 + c] bf16   (transpose-convert)
// ---------------------------------------------------------------------------
__global__ __launch_bounds__(256) void k_fl_t(const float* __restrict__ fl,
                                              unsigned short* __restrict__ Xb) {
    __shared__ unsigned short s[32][68];
    int b = blockIdx.z, c0 = blockIdx.y * 32, n0 = blockIdx.x * 64;
    int tx = threadIdx.x & 63, ty = threadIdx.x >> 6;       // 64 x 4
    const float* src = fl + ((size_t)b * CL + c0) * NL + n0;
#pragma unroll
    for (int i = 0; i < 8; i++) {
        int c = ty * 8 + i;
        s[c][tx] = f2bf(src[(size_t)c * NL + tx]);
    }
    __syncthreads();
    int n = threadIdx.x >> 2, q = threadIdx.x & 3;
    ushort4b o0, o1;
#pragma unroll
    for (int e = 0; e < 4; e++) o0[e] = s[q * 8 + e][n];
#pragma unroll
    for (int e = 0; e < 4; e++) o1[e] = s[q * 8 + 4 + e][n];
    unsigned short* dst = Xb + ((size_t)b * NL + n0 + n) * K0 + CHH + c0 + q * 8;
    *(ushort4b*)dst = o0;
    *(ushort4b*)(dst + 4) = o1;
}

// ---------------------------------------------------------------------------
// f32 -> bf16 convert for both weight matrices (one launch)
// ---------------------------------------------------------------------------
__global__ __launch_bounds__(256) void k_cvt2(const float* __restrict__ s0,
                                              unsigned short* __restrict__ d0, int n0,
                                              const float* __restrict__ s1,
                                              unsigned short* __restrict__ d1, int n1) {
    int i = blockIdx.x * 256 + threadIdx.x;
    if (i < n0) d0[i] = f2bf(s0[i]);
    else if (i < n0 + n1) d1[i - n0] = f2bf(s1[i - n0]);
}

// ---------------------------------------------------------------------------
// MFMA GEMM: Y[b][n][m] = bf16( sum_k W[m][k]*X[n][k] + bias[m] ), X n-major.
// 128x128 tile, BK=32, 4 waves, XOR-swizzled LDS, double buffer.
// 1-D grid (1024) with XCD-paired decode: the two m-tiles sharing an X panel
// sit 8 apart in dispatch order (same XCD under round-robin) -> X L2 reuse.
// ---------------------------------------------------------------------------
__device__ inline int swz(int r, int cb) {
    return r * 32 + ((cb ^ ((r >> 1) & 3)) << 3);   // short index, 16B blocks
}

template <int K>
__global__ __launch_bounds__(256) void k_gemmb(const unsigned short* __restrict__ X,
                                               const unsigned short* __restrict__ Wb,
                                               const float* __restrict__ bias,
                                               unsigned short* __restrict__ Y) {
    __shared__ __align__(16) unsigned short sA[2][128 * 32];
    __shared__ __align__(16) unsigned short sB[2][128 * 32];

    int t = blockIdx.x;               // 0..1023
    int xcd = t & 7, i = t >> 3;      // i: 0..127 within XCD
    int m0 = (i & 1) * 128;           // pair (m0, m0+128) separated by 8 in t
    int nb = i >> 1;                  // 0..63
    int n0 = (nb & 31) * 128;
    int b  = xcd * 2 + (nb >> 5);

    int tid = threadIdx.x;
    int lane = tid & 63;
    int wid = tid >> 6;
    int wm = wid >> 1, wn = wid & 1;

    int sr = tid >> 2;          // staging row 0..63 (and +64)
    int scb = tid & 3;          // staging 16B block
    int swA0 = swz(sr, scb), swA1 = swz(sr + 64, scb);

    const unsigned short* Wt = Wb + (size_t)m0 * K + scb * 8;
    const unsigned short* Xt = X + ((size_t)b * NL + n0) * K + scb * 8;

    f32x4 acc[4][4] = {};

    bfrag a0 = *(const bfrag*)&Wt[(size_t)sr * K];
    bfrag a1 = *(const bfrag*)&Wt[(size_t)(sr + 64) * K];
    bfrag b0 = *(const bfrag*)&Xt[(size_t)sr * K];
    bfrag b1 = *(const bfrag*)&Xt[(size_t)(sr + 64) * K];
    *(bfrag*)&sA[0][swA0] = a0;
    *(bfrag*)&sA[0][swA1] = a1;
    *(bfrag*)&sB[0][swA0] = b0;
    *(bfrag*)&sB[0][swA1] = b1;
    __syncthreads();

    const int nkt = K / 32;
    int cur = 0;
#pragma unroll 2
    for (int tt = 0; tt < nkt; tt++) {
        bfrag na0, na1, nb0, nb1;
        bool more = (tt + 1 < nkt);
        if (more) {
            int kk = (tt + 1) * 32;
            na0 = *(const bfrag*)&Wt[(size_t)sr * K + kk];
            na1 = *(const bfrag*)&Wt[(size_t)(sr + 64) * K + kk];
            nb0 = *(const bfrag*)&Xt[(size_t)sr * K + kk];
            nb1 = *(const bfrag*)&Xt[(size_t)(sr + 64) * K + kk];
        }
        bfrag af[4], bf[4];
#pragma unroll
        for (int mi = 0; mi < 4; mi++) {
            int r = wm * 64 + mi * 16 + (lane & 15);
            af[mi] = *(const bfrag*)&sA[cur][swz(r, lane >> 4)];
        }
#pragma unroll
        for (int ni = 0; ni < 4; ni++) {
            int r = wn * 64 + ni * 16 + (lane & 15);
            bf[ni] = *(const bfrag*)&sB[cur][swz(r, lane >> 4)];
        }
#pragma unroll
        for (int mi = 0; mi < 4; mi++)
#pragma unroll
            for (int ni = 0; ni < 4; ni++)
                acc[mi][ni] = __builtin_amdgcn_mfma_f32_16x16x32_bf16(
                    af[mi], bf[ni], acc[mi][ni], 0, 0, 0);
        if (more) {
            *(bfrag*)&sA[cur ^ 1][swA0] = na0;
            *(bfrag*)&sA[cur ^ 1][swA1] = na1;
            *(bfrag*)&sB[cur ^ 1][swA0] = nb0;
            *(bfrag*)&sB[cur ^ 1][swA1] = nb1;
            __syncthreads();
            cur ^= 1;
        }
    }

    // C frag: col = lane&15 (n), row = (lane>>4)*4 + j (m)
    int col = lane & 15, rg = (lane >> 4) << 2;
#pragma unroll
    for (int mi = 0; mi < 4; mi++) {
        int m = m0 + wm * 64 + mi * 16 + rg;
        f32x4 bv = *(const f32x4*)&bias[m];
#pragma unroll
        for (int ni = 0; ni < 4; ni++) {
            int n = n0 + wn * 64 + ni * 16 + col;
            f32x4 c = acc[mi][ni];
            ushort4b o;
            o[0] = f2bf(c[0] + bv[0]); o[1] = f2bf(c[1] + bv[1]);
            o[2] = f2bf(c[2] + bv[2]); o[3] = f2bf(c[3] + bv[3]);
            *(ushort4b*)&Y[((size_t)b * NL + n) * CO + m] = o;
        }
    }
}

// ---------------------------------------------------------------------------
// stats over n-major bf16 (65536 rows x 256 ch) -> atomic partial sums
// (block-level reduction first: 512 atomics total per pass)
// ---------------------------------------------------------------------------
__global__ __launch_bounds__(256) void k_stats(const unsigned short* __restrict__ y,
                                               float* __restrict__ psum,
                                               float* __restrict__ psq) {
    int r0 = blockIdx.x * 256;
    int lane = threadIdx.x & 63, wid = threadIdx.x >> 6;
    float s[4] = {0, 0, 0, 0}, q[4] = {0, 0, 0, 0};
    for (int j = 0; j < 64; j++) {
        int r = r0 + wid * 64 + j;
        ushort4b v = *(const ushort4b*)&y[(size_t)r * CO + lane * 4];
#pragma unroll
        for (int e = 0; e < 4; e++) {
            float f = bf2f(v[e]);
            s[e] += f; q[e] += f * f;
        }
    }
    __shared__ float ls[4][256], lq[4][256];
#pragma unroll
    for (int e = 0; e < 4; e++) {
        ls[wid][lane * 4 + e] = s[e];
        lq[wid][lane * 4 + e] = q[e];
    }
    __syncthreads();
    int c = threadIdx.x;
    float S = ls[0][c] + ls[1][c] + ls[2][c] + ls[3][c];
    float Q = lq[0][c] + lq[1][c] + lq[2][c] + lq[3][c];
    atomicAdd(&psum[c], S);
    atomicAdd(&psq[c], Q);
}

__global__ void k_fin(const float* __restrict__ psum, const float* __restrict__ psq,
                      const float* __restrict__ gamma, const float* __restrict__ beta,
                      float* __restrict__ scale, float* __restrict__ shift) {
    int c = threadIdx.x;
    float N = (float)(BB * NL);
    float mean = psum[c] / N;
    float var = psq[c] / N - mean * mean;
    float sc = gamma[c] / sqrtf(var + BN_EPS);
    scale[c] = sc;
    shift[c] = beta[c] - mean * sc;
}

// ---------------------------------------------------------------------------
// BN0 + ReLU in place on n-major bf16 y0
// ---------------------------------------------------------------------------
__global__ __launch_bounds__(256) void k_bn0(unsigned short* __restrict__ y,
                                             const float* __restrict__ scale,
                                             const float* __restrict__ shift) {
    size_t i = (size_t)blockIdx.x * 256 + threadIdx.x;      // short8 index
    unsigned short* p = y + i * 8;
    int cb = (int)(i & 31) * 8;
    bfrag v = *(bfrag*)p;
    f32x4 s0 = *(const f32x4*)&scale[cb], s1 = *(const f32x4*)&scale[cb + 4];
    f32x4 h0 = *(const f32x4*)&shift[cb], h1 = *(const f32x4*)&shift[cb + 4];
    bfrag o;
#pragma unroll
    for (int e = 0; e < 4; e++)
        o[e] = (short)f2bf(fmaxf(fmaf(s0[e], bf2f((unsigned short)v[e]), h0[e]), 0.f));
#pragma unroll
    for (int e = 0; e < 4; e++)
        o[4 + e] = (short)f2bf(fmaxf(fmaf(s1[e], bf2f((unsigned short)v[4 + e]), h1[e]), 0.f));
    *(bfrag*)p = o;
}

// ---------------------------------------------------------------------------
// final: read y1 bf16 [b][n][m], BN1+ReLU, transpose-write f32 out [b][m][n]
// ---------------------------------------------------------------------------
__global__ __launch_bounds__(256) void k_out(const unsigned short* __restrict__ y1,
                                             const float* __restrict__ scale,
                                             const float* __restrict__ shift,
                                             float* __restrict__ out) {
    __shared__ float s[64][65];
    int b = blockIdx.z, m0 = blockIdx.y * 64, n0 = blockIdx.x * 64;
    int r = threadIdx.x >> 3;            // 0..31
    int mq = (threadIdx.x & 7) * 8;      // 0..56
#pragma unroll
    for (int it = 0; it < 2; it++) {
        int row = r + it * 32;
        bfrag v = *(const bfrag*)&y1[((size_t)b * NL + n0 + row) * CO + m0 + mq];
#pragma unroll
        for (int e = 0; e < 8; e++) {
            int m = mq + e;
            float f = bf2f((unsigned short)v[e]);
            s[m][row] = fmaxf(fmaf(scale[m0 + m], f, shift[m0 + m]), 0.f);
        }
    }
    __syncthreads();
    int m = threadIdx.x >> 2, nb = (threadIdx.x & 3) * 16;
    float* orow = out + ((size_t)b * CO + m0 + m) * NL + n0 + nb;
#pragma unroll
    for (int i = 0; i < 16; i += 4) {
        float4 v = make_float4(s[m][nb + i], s[m][nb + i + 1],
                               s[m][nb + i + 2], s[m][nb + i + 3]);
        *(float4*)&orow[i] = v;
    }
}

// ---------------------------------------------------------------------------
extern "C" void kernel_launch(void* const* d_in, const int* in_sizes, int n_in,
                              void* d_out, int out_size, void* d_ws, size_t ws_size,
                              hipStream_t stream) {
    const float* xyz_low   = (const float*)d_in[0];
    const float* xyz_high  = (const float*)d_in[1];
    const float* feat_low  = (const float*)d_in[2];
    const float* feat_high = (const float*)d_in[3];
    const float* W0  = (const float*)d_in[4];
    const float* b0  = (const float*)d_in[5];
    const float* g0  = (const float*)d_in[6];
    const float* be0 = (const float*)d_in[7];
    const float* W1  = (const float*)d_in[8];
    const float* b1  = (const float*)d_in[9];
    const float* g1  = (const float*)d_in[10];
    const float* be1 = (const float*)d_in[11];
    float* out = (float*)d_out;

    char* ws = (char*)d_ws;
    // [Xb 48MB][y0 32MB][y1 32MB (fT bf16 aliases start; fT dead before gemm1)]
    unsigned short* Xb  = (unsigned short*)ws;
    unsigned short* y0  = (unsigned short*)(ws + ((size_t)48 << 20));
    unsigned short* y1  = (unsigned short*)(ws + ((size_t)80 << 20));
    unsigned short* fT  = (unsigned short*)(ws + ((size_t)80 << 20));
    char* tail          = ws + ((size_t)112 << 20);
    int*    idx   = (int*)tail;                       // 768 KB
    float*  wgt   = (float*)(tail + 786432);          // 768 KB
    float4* cand4 = (float4*)(tail + 2 * 786432);     // 256 KB
    unsigned short* Wb0 = (unsigned short*)(tail + 2 * 786432 + 262144);
    unsigned short* Wb1 = Wb0 + CO * K0;
    float* prm    = (float*)(Wb1 + CO * K1);
    float* psum0 = prm,        *psq0 = prm + 256;
    float* psum1 = prm + 512,  *psq1 = prm + 768;
    float* scale0 = prm + 1024, *shift0 = prm + 1280;
    float* scale1 = prm + 1536, *shift1 = prm + 1792;

    k_cvt2<<<(CO * (K0 + K1) + 255) / 256, 256, 0, stream>>>(
        W0, Wb0, CO * K0, W1, Wb1, CO * K1);
    k_prep<<<(BB * NH + 255) / 256, 256, 0, stream>>>(xyz_high, cand4);
    k_transpose_fh<<<dim3(NH / 32, CHH / 32, BB), 256, 0, stream>>>(feat_high, fT);
    k_knn<<<dim3(NL / 64, BB), 256, 0, stream>>>(xyz_low, cand4, idx, wgt);
    k_interp<<<dim3(NL / 16, BB), 256, 0, stream>>>(fT, idx, wgt, Xb);
    k_fl_t<<<dim3(NL / 64, CL / 32, BB), 256, 0, stream>>>(feat_low, Xb);
    hipMemsetAsync(prm, 0, 1024 * sizeof(float), stream);

    k_gemmb<K0><<<1024, 256, 0, stream>>>(Xb, Wb0, b0, y0);
    k_stats<<<256, 256, 0, stream>>>(y0, psum0, psq0);
    k_fin<<<1, 256, 0, stream>>>(psum0, psq0, g0, be0, scale0, shift0);
    k_bn0<<<(BB * NL * CO / 8) / 256, 256, 0, stream>>>(y0, scale0, shift0);
    k_gemmb<K1><<<1024, 256, 0, stream>>>(y0, Wb1, b1, y1);
    k_stats<<<256, 256, 0, stream>>>(y1, psum1, psq1);
    k_fin<<<1, 256, 0, stream>>>(psum1, psq1, g1, be1, scale1, shift1);
    k_out<<<dim3(NL / 64, CO / 64, BB), 256, 0, stream>>>(y1, scale1, shift1, out);
}

// Round 8
// 176.395 us; speedup vs baseline: 2.1354x; 1.1259x over previous
//
#include <hip/hip_runtime.h>
#include <math.h>

#define BB 16
#define NL 4096
#define NH 1024
#define CL 128
#define CHH 256
#define K0 384
#define K1 256
#define CO 256
#define BN_EPS 1e-5f

typedef __attribute__((ext_vector_type(8))) short bfrag;     // 8 bf16
typedef __attribute__((ext_vector_type(4))) float f32x4;
typedef __attribute__((ext_vector_type(4))) unsigned short ushort4b;

__device__ inline unsigned short f2bf(float f) {
    unsigned int u = __builtin_bit_cast(unsigned int, f);
    u += 0x7fffu + ((u >> 16) & 1u);                 // RNE
    return (unsigned short)(u >> 16);
}
__device__ inline float bf2f(unsigned short h) {
    unsigned int u = ((unsigned int)h) << 16;
    return __builtin_bit_cast(float, u);
}

// ---------------------------------------------------------------------------
// setup: weights f32->bf16 + candidate packing (one launch)
// ---------------------------------------------------------------------------
__global__ __launch_bounds__(256) void k_setup(const float* __restrict__ W0s,
                                               unsigned short* __restrict__ Wb0,
                                               const float* __restrict__ W1s,
                                               unsigned short* __restrict__ Wb1,
                                               const float* __restrict__ xyzh,
                                               float4* __restrict__ cand4) {
    int i = blockIdx.x * 256 + threadIdx.x;
    if (i < CO * K0) Wb0[i] = f2bf(W0s[i]);
    if (i < CO * K1) Wb1[i] = f2bf(W1s[i]);
    if (i < BB * NH) {
        float x = xyzh[3 * i], y = xyzh[3 * i + 1], z = xyzh[3 * i + 2];
        float ss = __fadd_rn(__fadd_rn(__fmul_rn(x, x), __fmul_rn(y, y)),
                             __fmul_rn(z, z));
        cand4[i] = make_float4(x, y, z, ss);
    }
}

// ---------------------------------------------------------------------------
// transpose feat_high (B, CH, NH) f32 -> fT (B, NH, CH) bf16
// ---------------------------------------------------------------------------
__global__ __launch_bounds__(256) void k_transpose_fh(const float* __restrict__ fh,
                                                      unsigned short* __restrict__ fT) {
    __shared__ float s[32][33];
    int b = blockIdx.z;
    int c0 = blockIdx.y * 32;
    int m0 = blockIdx.x * 32;
    int tx = threadIdx.x % 32, ty = threadIdx.x / 32;
    const float* src = fh + (size_t)b * CHH * NH;
    unsigned short* dst = fT + (size_t)b * NH * CHH;
#pragma unroll
    for (int j = 0; j < 4; j++)
        s[ty + 8 * j][tx] = src[(size_t)(c0 + ty + 8 * j) * NH + m0 + tx];
    __syncthreads();
    int mi = threadIdx.x >> 3;           // 0..31 point-in-tile
    int cp = threadIdx.x & 7;            // 0..7 channel-pair group
#pragma unroll
    for (int h = 0; h < 2; h++) {
        int ci = (cp + 8 * h) * 2;
        unsigned int o = (unsigned int)f2bf(s[ci][mi]) |
                         ((unsigned int)f2bf(s[ci + 1][mi]) << 16);
        *(unsigned int*)&dst[(size_t)(m0 + mi) * CHH + c0 + ci] = o;
    }
}

// ---------------------------------------------------------------------------
// 3-NN search v7: wave = segment (broadcast LDS, conflict-free), lane = point.
// min/med3 value update; clamp hoisted to merge (duplicate-point-only risk).
// Exact __f*_rn distance chain as reference; stable merge across segments.
// ---------------------------------------------------------------------------
__global__ __launch_bounds__(256) void k_knn(const float* __restrict__ xyzl,
                                             const float4* __restrict__ cand4,
                                             int* __restrict__ idx,
                                             float* __restrict__ wgt) {
    __shared__ float4 cnd[NH];           // 16 KB
    __shared__ float tls[4][64][3];
    __shared__ int   ils[4][64][3];

    int b = blockIdx.y;
    for (int p = threadIdx.x; p < NH; p += 256)
        cnd[p] = cand4[(size_t)b * NH + p];
    __syncthreads();

    int lane = threadIdx.x & 63;
    int w = threadIdx.x >> 6;            // segment
    int n = blockIdx.x * 64 + lane;

    const float* xl = xyzl + ((size_t)b * NL + n) * 3;
    float l0 = xl[0], l1 = xl[1], l2 = xl[2];
    float a = __fadd_rn(__fadd_rn(__fmul_rn(l0, l0), __fmul_rn(l1, l1)),
                        __fmul_rn(l2, l2));

    float t0 = INFINITY, t1 = INFINITY, t2 = INFINITY;
    int i0 = 0, i1 = 0, i2 = 0;
    int mb = w * 256;
#pragma unroll 8
    for (int j = 0; j < 256; j++) {
        float4 c = cnd[mb + j];          // broadcast read
        int m = mb + j;
        float dot = __fadd_rn(__fadd_rn(__fmul_rn(l0, c.x), __fmul_rn(l1, c.y)),
                              __fmul_rn(l2, c.z));
        float dd = __fsub_rn(__fadd_rn(a, c.w), __fmul_rn(2.0f, dot));
        bool c0 = dd < t0, c1 = dd < t1, c2 = dd < t2;
        float nt0 = fminf(dd, t0);
        float nt1 = __builtin_amdgcn_fmed3f(dd, t0, t1);
        float nt2 = __builtin_amdgcn_fmed3f(dd, t1, t2);
        i2 = c1 ? i1 : (c2 ? m : i2);
        i1 = c0 ? i0 : (c1 ? m : i1);
        i0 = c0 ? m : i0;
        t0 = nt0; t1 = nt1; t2 = nt2;
    }
    tls[w][lane][0] = t0; tls[w][lane][1] = t1; tls[w][lane][2] = t2;
    ils[w][lane][0] = i0; ils[w][lane][1] = i1; ils[w][lane][2] = i2;
    __syncthreads();

    if (threadIdx.x < 64) {
        int p = threadIdx.x;
        float u0 = tls[0][p][0], u1 = tls[0][p][1], u2 = tls[0][p][2];
        int   j0 = ils[0][p][0], j1 = ils[0][p][1], j2 = ils[0][p][2];
#pragma unroll
        for (int sg = 1; sg < 4; sg++) {
#pragma unroll
            for (int e = 0; e < 3; e++) {
                float dd = tls[sg][p][e];
                int m = ils[sg][p][e];
                bool c0 = dd < u0, c1 = dd < u1, c2 = dd < u2;
                u2 = c1 ? u1 : (c2 ? dd : u2);
                j2 = c1 ? j1 : (c2 ? m : j2);
                u1 = c0 ? u0 : (c1 ? dd : u1);
                j1 = c0 ? j0 : (c1 ? m : j1);
                u0 = c0 ? dd : u0;
                j0 = c0 ? m : j0;
            }
        }
        u0 = fmaxf(u0, 0.0f); u1 = fmaxf(u1, 0.0f); u2 = fmaxf(u2, 0.0f);
        float d0 = sqrtf(u0), d1 = sqrtf(u1), d2 = sqrtf(u2);
        float w0 = 1.0f / fmaxf(d0, 1e-8f);
        float w1 = 1.0f / fmaxf(d1, 1e-8f);
        float w2 = 1.0f / fmaxf(d2, 1e-8f);
        float wsum = __fadd_rn(__fadd_rn(w0, w1), w2);
        w0 /= wsum; w1 /= wsum; w2 /= wsum;
        int nn = blockIdx.x * 64 + p;
        size_t base = ((size_t)b * NL + nn) * 3;
        idx[base] = j0; idx[base + 1] = j1; idx[base + 2] = j2;
        wgt[base] = w0; wgt[base + 1] = w1; wgt[base + 2] = w2;
    }
}

// ---------------------------------------------------------------------------
// interpolate -> Xb[b][n][c] bf16, c in [0, 256); fT is bf16
// ---------------------------------------------------------------------------
__global__ __launch_bounds__(256) void k_interp(const unsigned short* __restrict__ fT,
                                                const int* __restrict__ idx,
                                                const float* __restrict__ wgt,
                                                unsigned short* __restrict__ Xb) {
    int b = blockIdx.y;
    int n0 = blockIdx.x * 16;
    int c = threadIdx.x;
    const unsigned short* fTb = fT + (size_t)b * NH * CHH;
    for (int j = 0; j < 16; j++) {
        size_t base = ((size_t)b * NL + n0 + j) * 3;
        int m0 = idx[base], m1 = idx[base + 1], m2 = idx[base + 2];
        float w0 = wgt[base], w1 = wgt[base + 1], w2 = wgt[base + 2];
        float f0 = bf2f(fTb[(size_t)m0 * CHH + c]);
        float f1 = bf2f(fTb[(size_t)m1 * CHH + c]);
        float f2 = bf2f(fTb[(size_t)m2 * CHH + c]);
        float f = __fadd_rn(__fadd_rn(__fmul_rn(w0, f0), __fmul_rn(w1, f1)),
                            __fmul_rn(w2, f2));
        Xb[((size_t)b * NL + n0 + j) * K0 + c] = f2bf(f);
    }
}

// ---------------------------------------------------------------------------
// feat_low (B, CL, NL) f32 -> Xb[b][n][256 + c] bf16   (transpose-convert)
// ---------------------------------------------------------------------------
__global__ __launch_bounds__(256) void k_fl_t(const float* __restrict__ fl,
                                              unsigned short* __restrict__ Xb) {
    __shared__ unsigned short s[32][68];
    int b = blockIdx.z, c0 = blockIdx.y * 32, n0 = blockIdx.x * 64;
    int tx = threadIdx.x & 63, ty = threadIdx.x >> 6;       // 64 x 4
    const float* src = fl + ((size_t)b * CL + c0) * NL + n0;
#pragma unroll
    for (int i = 0; i < 8; i++) {
        int c = ty * 8 + i;
        s[c][tx] = f2bf(src[(size_t)c * NL + tx]);
    }
    __syncthreads();
    int n = threadIdx.x >> 2, q = threadIdx.x & 3;
    ushort4b o0, o1;
#pragma unroll
    for (int e = 0; e < 4; e++) o0[e] = s[q * 8 + e][n];
#pragma unroll
    for (int e = 0; e < 4; e++) o1[e] = s[q * 8 + 4 + e][n];
    unsigned short* dst = Xb + ((size_t)b * NL + n0 + n) * K0 + CHH + c0 + q * 8;
    *(ushort4b*)dst = o0;
    *(ushort4b*)(dst + 4) = o1;
}

// ---------------------------------------------------------------------------
// BN0+ReLU transform on an 8-element bf16 fragment (bit-identical to old k_bn0)
// ---------------------------------------------------------------------------
__device__ inline bfrag bnrelu8(bfrag v, f32x4 s0, f32x4 s1, f32x4 h0, f32x4 h1) {
    bfrag o;
#pragma unroll
    for (int e = 0; e < 4; e++)
        o[e] = (short)f2bf(fmaxf(fmaf(s0[e], bf2f((unsigned short)v[e]), h0[e]), 0.f));
#pragma unroll
    for (int e = 0; e < 4; e++)
        o[4 + e] = (short)f2bf(fmaxf(fmaf(s1[e], bf2f((unsigned short)v[4 + e]), h1[e]), 0.f));
    return o;
}

// ---------------------------------------------------------------------------
// MFMA GEMM: Y[b][n][m] = bf16( sum_k W[m][k]*X'[n][k] + bias[m] ), X n-major.
// X' = BN? relu(scale*X+shift) : X  (BN fused on B-staging, channel = k).
// Epilogue: per-block per-channel partial stats (f32, pre-rounding) stored to
// DISTINCT addresses psumT/psqT[m][pi*2+wn] (no atomics).
// 128x128 tile, BK=32, 4 waves, XOR-swizzled LDS, dbuf, XCD-paired 1-D grid.
// ---------------------------------------------------------------------------
__device__ inline int swz(int r, int cb) {
    return r * 32 + ((cb ^ ((r >> 1) & 3)) << 3);   // short index, 16B blocks
}

template <int K, bool BN>
__global__ __launch_bounds__(256) void k_gemmb(const unsigned short* __restrict__ X,
                                               const unsigned short* __restrict__ Wb,
                                               const float* __restrict__ bias,
                                               const float* __restrict__ bnsc,
                                               const float* __restrict__ bnsh,
                                               unsigned short* __restrict__ Y,
                                               float* __restrict__ psumT,
                                               float* __restrict__ psqT) {
    __shared__ __align__(16) unsigned short sA[2][128 * 32];
    __shared__ __align__(16) unsigned short sB[2][128 * 32];

    int t = blockIdx.x;               // 0..1023
    int xcd = t & 7, i = t >> 3;      // i: 0..127 within XCD
    int m0 = (i & 1) * 128;           // pair (m0, m0+128) separated by 8 in t
    int nb = i >> 1;                  // 0..63
    int n0 = (nb & 31) * 128;
    int b  = xcd * 2 + (nb >> 5);
    int pi2 = (b * 32 + (nb & 31)) * 2;

    int tid = threadIdx.x;
    int lane = tid & 63;
    int wid = tid >> 6;
    int wm = wid >> 1, wn = wid & 1;

    int sr = tid >> 2;          // staging row 0..63 (and +64)
    int scb = tid & 3;          // staging 16B block
    int swA0 = swz(sr, scb), swA1 = swz(sr + 64, scb);

    const unsigned short* Wt = Wb + (size_t)m0 * K + scb * 8;
    const unsigned short* Xt = X + ((size_t)b * NL + n0) * K + scb * 8;

    f32x4 acc[4][4] = {};

    bfrag a0 = *(const bfrag*)&Wt[(size_t)sr * K];
    bfrag a1 = *(const bfrag*)&Wt[(size_t)(sr + 64) * K];
    bfrag b0 = *(const bfrag*)&Xt[(size_t)sr * K];
    bfrag b1 = *(const bfrag*)&Xt[(size_t)(sr + 64) * K];
    if (BN) {
        int cg = scb * 8;
        f32x4 sc0 = *(const f32x4*)&bnsc[cg], sc1 = *(const f32x4*)&bnsc[cg + 4];
        f32x4 sh0 = *(const f32x4*)&bnsh[cg], sh1 = *(const f32x4*)&bnsh[cg + 4];
        b0 = bnrelu8(b0, sc0, sc1, sh0, sh1);
        b1 = bnrelu8(b1, sc0, sc1, sh0, sh1);
    }
    *(bfrag*)&sA[0][swA0] = a0;
    *(bfrag*)&sA[0][swA1] = a1;
    *(bfrag*)&sB[0][swA0] = b0;
    *(bfrag*)&sB[0][swA1] = b1;
    __syncthreads();

    const int nkt = K / 32;
    int cur = 0;
#pragma unroll 2
    for (int tt = 0; tt < nkt; tt++) {
        bfrag na0, na1, nb0, nb1;
        bool more = (tt + 1 < nkt);
        if (more) {
            int kk = (tt + 1) * 32;
            na0 = *(const bfrag*)&Wt[(size_t)sr * K + kk];
            na1 = *(const bfrag*)&Wt[(size_t)(sr + 64) * K + kk];
            nb0 = *(const bfrag*)&Xt[(size_t)sr * K + kk];
            nb1 = *(const bfrag*)&Xt[(size_t)(sr + 64) * K + kk];
            if (BN) {
                int cg = kk + scb * 8;
                f32x4 sc0 = *(const f32x4*)&bnsc[cg], sc1 = *(const f32x4*)&bnsc[cg + 4];
                f32x4 sh0 = *(const f32x4*)&bnsh[cg], sh1 = *(const f32x4*)&bnsh[cg + 4];
                nb0 = bnrelu8(nb0, sc0, sc1, sh0, sh1);
                nb1 = bnrelu8(nb1, sc0, sc1, sh0, sh1);
            }
        }
        bfrag af[4], bf[4];
#pragma unroll
        for (int mi = 0; mi < 4; mi++) {
            int r = wm * 64 + mi * 16 + (lane & 15);
            af[mi] = *(const bfrag*)&sA[cur][swz(r, lane >> 4)];
        }
#pragma unroll
        for (int ni = 0; ni < 4; ni++) {
            int r = wn * 64 + ni * 16 + (lane & 15);
            bf[ni] = *(const bfrag*)&sB[cur][swz(r, lane >> 4)];
        }
#pragma unroll
        for (int mi = 0; mi < 4; mi++)
#pragma unroll
            for (int ni = 0; ni < 4; ni++)
                acc[mi][ni] = __builtin_amdgcn_mfma_f32_16x16x32_bf16(
                    af[mi], bf[ni], acc[mi][ni], 0, 0, 0);
        if (more) {
            *(bfrag*)&sA[cur ^ 1][swA0] = na0;
            *(bfrag*)&sA[cur ^ 1][swA1] = na1;
            *(bfrag*)&sB[cur ^ 1][swA0] = nb0;
            *(bfrag*)&sB[cur ^ 1][swA1] = nb1;
            __syncthreads();
            cur ^= 1;
        }
    }

    // C frag: col = lane&15 (n), row = (lane>>4)*4 + j (m)
    int col = lane & 15, rg = (lane >> 4) << 2;
#pragma unroll
    for (int mi = 0; mi < 4; mi++) {
        int m = m0 + wm * 64 + mi * 16 + rg;
        f32x4 bv = *(const f32x4*)&bias[m];
        f32x4 sacc = {0.f, 0.f, 0.f, 0.f}, qacc = {0.f, 0.f, 0.f, 0.f};
#pragma unroll
        for (int ni = 0; ni < 4; ni++) {
            int n = n0 + wn * 64 + ni * 16 + col;
            f32x4 c = acc[mi][ni];
            ushort4b o;
#pragma unroll
            for (int j = 0; j < 4; j++) {
                float sv = c[j] + bv[j];
                o[j] = f2bf(sv);
                sacc[j] += sv;
                qacc[j] += sv * sv;
            }
            *(ushort4b*)&Y[((size_t)b * NL + n) * CO + m] = o;
        }
#pragma unroll
        for (int j = 0; j < 4; j++) {
            float s = sacc[j], q = qacc[j];
#pragma unroll
            for (int off = 1; off < 16; off <<= 1) {
                s += __shfl_xor(s, off, 64);
                q += __shfl_xor(q, off, 64);
            }
            if (col == 0) {
                psumT[(size_t)(m + j) * 1024 + pi2 + wn] = s;
                psqT[(size_t)(m + j) * 1024 + pi2 + wn] = q;
            }
        }
    }
}

// ---------------------------------------------------------------------------
// reduce per-block partials -> scale/shift. One block per channel; contiguous.
// ---------------------------------------------------------------------------
__global__ __launch_bounds__(256) void k_fin(const float* __restrict__ psumT,
                                             const float* __restrict__ psqT,
                                             const float* __restrict__ gamma,
                                             const float* __restrict__ beta,
                                             float* __restrict__ scale,
                                             float* __restrict__ shift) {
    int c = blockIdx.x;
    const float* ps = psumT + (size_t)c * 1024;
    const float* pq = psqT + (size_t)c * 1024;
    float s = 0.f, q = 0.f;
    for (int i = threadIdx.x; i < 1024; i += 256) { s += ps[i]; q += pq[i]; }
#pragma unroll
    for (int off = 1; off < 64; off <<= 1) {
        s += __shfl_xor(s, off, 64);
        q += __shfl_xor(q, off, 64);
    }
    __shared__ float ls[4], lq[4];
    if ((threadIdx.x & 63) == 0) { ls[threadIdx.x >> 6] = s; lq[threadIdx.x >> 6] = q; }
    __syncthreads();
    if (threadIdx.x == 0) {
        float S = ls[0] + ls[1] + ls[2] + ls[3];
        float Q = lq[0] + lq[1] + lq[2] + lq[3];
        float N = (float)(BB * NL);
        float mean = S / N;
        float var = Q / N - mean * mean;
        float sc = gamma[c] / sqrtf(var + BN_EPS);
        scale[c] = sc;
        shift[c] = beta[c] - mean * sc;
    }
}

// ---------------------------------------------------------------------------
// final: read y1 bf16 [b][n][m], BN1+ReLU, transpose-write f32 out [b][m][n]
// ---------------------------------------------------------------------------
__global__ __launch_bounds__(256) void k_out(const unsigned short* __restrict__ y1,
                                             const float* __restrict__ scale,
                                             const float* __restrict__ shift,
                                             float* __restrict__ out) {
    __shared__ float s[64][65];
    int b = blockIdx.z, m0 = blockIdx.y * 64, n0 = blockIdx.x * 64;
    int r = threadIdx.x >> 3;            // 0..31
    int mq = (threadIdx.x & 7) * 8;      // 0..56
#pragma unroll
    for (int it = 0; it < 2; it++) {
        int row = r + it * 32;
        bfrag v = *(const bfrag*)&y1[((size_t)b * NL + n0 + row) * CO + m0 + mq];
#pragma unroll
        for (int e = 0; e < 8; e++) {
            int m = mq + e;
            float f = bf2f((unsigned short)v[e]);
            s[m][row] = fmaxf(fmaf(scale[m0 + m], f, shift[m0 + m]), 0.f);
        }
    }
    __syncthreads();
    int m = threadIdx.x >> 2, nb = (threadIdx.x & 3) * 16;
    float* orow = out + ((size_t)b * CO + m0 + m) * NL + n0 + nb;
#pragma unroll
    for (int i = 0; i < 16; i += 4) {
        float4 v = make_float4(s[m][nb + i], s[m][nb + i + 1],
                               s[m][nb + i + 2], s[m][nb + i + 3]);
        *(float4*)&orow[i] = v;
    }
}

// ---------------------------------------------------------------------------
extern "C" void kernel_launch(void* const* d_in, const int* in_sizes, int n_in,
                              void* d_out, int out_size, void* d_ws, size_t ws_size,
                              hipStream_t stream) {
    const float* xyz_low   = (const float*)d_in[0];
    const float* xyz_high  = (const float*)d_in[1];
    const float* feat_low  = (const float*)d_in[2];
    const float* feat_high = (const float*)d_in[3];
    const float* W0  = (const float*)d_in[4];
    const float* b0  = (const float*)d_in[5];
    const float* g0  = (const float*)d_in[6];
    const float* be0 = (const float*)d_in[7];
    const float* W1  = (const float*)d_in[8];
    const float* b1  = (const float*)d_in[9];
    const float* g1  = (const float*)d_in[10];
    const float* be1 = (const float*)d_in[11];
    float* out = (float*)d_out;

    char* ws = (char*)d_ws;
    // [Xb 48MB][y0 32MB][y1 32MB (fT bf16 aliases start; fT dead before gemm1)]
    unsigned short* Xb  = (unsigned short*)ws;
    unsigned short* y0  = (unsigned short*)(ws + ((size_t)48 << 20));
    unsigned short* y1  = (unsigned short*)(ws + ((size_t)80 << 20));
    unsigned short* fT  = (unsigned short*)(ws + ((size_t)80 << 20));
    char* tail          = ws + ((size_t)112 << 20);
    int*    idx   = (int*)tail;                       // 768 KB
    float*  wgt   = (float*)(tail + 786432);          // 768 KB
    float4* cand4 = (float4*)(tail + 2 * 786432);     // 256 KB
    unsigned short* Wb0 = (unsigned short*)(tail + 2 * 786432 + 262144);
    unsigned short* Wb1 = Wb0 + CO * K0;              // +192 KB
    char* tail2   = (char*)(Wb1 + CO * K1);           // +128 KB
    float* psumT0 = (float*)tail2;                    // 1 MB  [256][1024]
    float* psqT0  = psumT0 + 256 * 1024;              // 1 MB
    float* psumT1 = psqT0 + 256 * 1024;               // 1 MB
    float* psqT1  = psumT1 + 256 * 1024;              // 1 MB
    float* prm    = psqT1 + 256 * 1024;
    float* scale0 = prm,        *shift0 = prm + 256;
    float* scale1 = prm + 512,  *shift1 = prm + 768;

    k_setup<<<(CO * K0 + 255) / 256, 256, 0, stream>>>(W0, Wb0, W1, Wb1,
                                                       xyz_high, cand4);
    k_transpose_fh<<<dim3(NH / 32, CHH / 32, BB), 256, 0, stream>>>(feat_high, fT);
    k_knn<<<dim3(NL / 64, BB), 256, 0, stream>>>(xyz_low, cand4, idx, wgt);
    k_interp<<<dim3(NL / 16, BB), 256, 0, stream>>>(fT, idx, wgt, Xb);
    k_fl_t<<<dim3(NL / 64, CL / 32, BB), 256, 0, stream>>>(feat_low, Xb);

    k_gemmb<K0, false><<<1024, 256, 0, stream>>>(Xb, Wb0, b0, nullptr, nullptr,
                                                 y0, psumT0, psqT0);
    k_fin<<<256, 256, 0, stream>>>(psumT0, psqT0, g0, be0, scale0, shift0);
    k_gemmb<K1, true><<<1024, 256, 0, stream>>>(y0, Wb1, b1, scale0, shift0,
                                                y1, psumT1, psqT1);
    k_fin<<<256, 256, 0, stream>>>(psumT1, psqT1, g1, be1, scale1, shift1);
    k_out<<<dim3(NL / 64, CO / 64, BB), 256, 0, stream>>>(y1, scale1, shift1, out);
}

// Round 9
// 157.742 us; speedup vs baseline: 2.3879x; 1.1183x over previous
//
#include <hip/hip_runtime.h>
#include <math.h>

#define BB 16
#define NL 4096
#define NH 1024
#define CL 128
#define CHH 256
#define K0 384
#define K1 256
#define CO 256
#define BN_EPS 1e-5f

typedef __attribute__((ext_vector_type(8))) short bfrag;     // 8 bf16
typedef __attribute__((ext_vector_type(4))) float f32x4;
typedef __attribute__((ext_vector_type(4))) unsigned short ushort4b;

__device__ inline unsigned short f2bf(float f) {
    unsigned int u = __builtin_bit_cast(unsigned int, f);
    u += 0x7fffu + ((u >> 16) & 1u);                 // RNE
    return (unsigned short)(u >> 16);
}
__device__ inline float bf2f(unsigned short h) {
    unsigned int u = ((unsigned int)h) << 16;
    return __builtin_bit_cast(float, u);
}

// ---------------------------------------------------------------------------
// setup: weights f32->bf16 + candidate packing (one launch)
// ---------------------------------------------------------------------------
__global__ __launch_bounds__(256) void k_setup(const float* __restrict__ W0s,
                                               unsigned short* __restrict__ Wb0,
                                               const float* __restrict__ W1s,
                                               unsigned short* __restrict__ Wb1,
                                               const float* __restrict__ xyzh,
                                               float4* __restrict__ cand4) {
    int i = blockIdx.x * 256 + threadIdx.x;
    if (i < CO * K0) Wb0[i] = f2bf(W0s[i]);
    if (i < CO * K1) Wb1[i] = f2bf(W1s[i]);
    if (i < BB * NH) {
        float x = xyzh[3 * i], y = xyzh[3 * i + 1], z = xyzh[3 * i + 2];
        float ss = __fadd_rn(__fadd_rn(__fmul_rn(x, x), __fmul_rn(y, y)),
                             __fmul_rn(z, z));
        cand4[i] = make_float4(x, y, z, ss);
    }
}

// ---------------------------------------------------------------------------
// transpose feat_high (B, CH, NH) f32 -> fT (B, NH, CH) bf16
// ---------------------------------------------------------------------------
__global__ __launch_bounds__(256) void k_transpose_fh(const float* __restrict__ fh,
                                                      unsigned short* __restrict__ fT) {
    __shared__ float s[32][33];
    int b = blockIdx.z;
    int c0 = blockIdx.y * 32;
    int m0 = blockIdx.x * 32;
    int tx = threadIdx.x % 32, ty = threadIdx.x / 32;
    const float* src = fh + (size_t)b * CHH * NH;
    unsigned short* dst = fT + (size_t)b * NH * CHH;
#pragma unroll
    for (int j = 0; j < 4; j++)
        s[ty + 8 * j][tx] = src[(size_t)(c0 + ty + 8 * j) * NH + m0 + tx];
    __syncthreads();
    int mi = threadIdx.x >> 3;           // 0..31 point-in-tile
    int cp = threadIdx.x & 7;            // 0..7 channel-pair group
#pragma unroll
    for (int h = 0; h < 2; h++) {
        int ci = (cp + 8 * h) * 2;
        unsigned int o = (unsigned int)f2bf(s[ci][mi]) |
                         ((unsigned int)f2bf(s[ci + 1][mi]) << 16);
        *(unsigned int*)&dst[(size_t)(m0 + mi) * CHH + c0 + ci] = o;
    }
}

// ---------------------------------------------------------------------------
// 3-NN search v7 (unchanged from round 8): wave = segment, broadcast LDS.
// ---------------------------------------------------------------------------
__global__ __launch_bounds__(256) void k_knn(const float* __restrict__ xyzl,
                                             const float4* __restrict__ cand4,
                                             int* __restrict__ idx,
                                             float* __restrict__ wgt) {
    __shared__ float4 cnd[NH];           // 16 KB
    __shared__ float tls[4][64][3];
    __shared__ int   ils[4][64][3];

    int b = blockIdx.y;
    for (int p = threadIdx.x; p < NH; p += 256)
        cnd[p] = cand4[(size_t)b * NH + p];
    __syncthreads();

    int lane = threadIdx.x & 63;
    int w = threadIdx.x >> 6;            // segment
    int n = blockIdx.x * 64 + lane;

    const float* xl = xyzl + ((size_t)b * NL + n) * 3;
    float l0 = xl[0], l1 = xl[1], l2 = xl[2];
    float a = __fadd_rn(__fadd_rn(__fmul_rn(l0, l0), __fmul_rn(l1, l1)),
                        __fmul_rn(l2, l2));

    float t0 = INFINITY, t1 = INFINITY, t2 = INFINITY;
    int i0 = 0, i1 = 0, i2 = 0;
    int mb = w * 256;
#pragma unroll 8
    for (int j = 0; j < 256; j++) {
        float4 c = cnd[mb + j];          // broadcast read
        int m = mb + j;
        float dot = __fadd_rn(__fadd_rn(__fmul_rn(l0, c.x), __fmul_rn(l1, c.y)),
                              __fmul_rn(l2, c.z));
        float dd = __fsub_rn(__fadd_rn(a, c.w), __fmul_rn(2.0f, dot));
        bool c0 = dd < t0, c1 = dd < t1, c2 = dd < t2;
        float nt0 = fminf(dd, t0);
        float nt1 = __builtin_amdgcn_fmed3f(dd, t0, t1);
        float nt2 = __builtin_amdgcn_fmed3f(dd, t1, t2);
        i2 = c1 ? i1 : (c2 ? m : i2);
        i1 = c0 ? i0 : (c1 ? m : i1);
        i0 = c0 ? m : i0;
        t0 = nt0; t1 = nt1; t2 = nt2;
    }
    tls[w][lane][0] = t0; tls[w][lane][1] = t1; tls[w][lane][2] = t2;
    ils[w][lane][0] = i0; ils[w][lane][1] = i1; ils[w][lane][2] = i2;
    __syncthreads();

    if (threadIdx.x < 64) {
        int p = threadIdx.x;
        float u0 = tls[0][p][0], u1 = tls[0][p][1], u2 = tls[0][p][2];
        int   j0 = ils[0][p][0], j1 = ils[0][p][1], j2 = ils[0][p][2];
#pragma unroll
        for (int sg = 1; sg < 4; sg++) {
#pragma unroll
            for (int e = 0; e < 3; e++) {
                float dd = tls[sg][p][e];
                int m = ils[sg][p][e];
                bool c0 = dd < u0, c1 = dd < u1, c2 = dd < u2;
                u2 = c1 ? u1 : (c2 ? dd : u2);
                j2 = c1 ? j1 : (c2 ? m : j2);
                u1 = c0 ? u0 : (c1 ? dd : u1);
                j1 = c0 ? j0 : (c1 ? m : j1);
                u0 = c0 ? dd : u0;
                j0 = c0 ? m : j0;
            }
        }
        u0 = fmaxf(u0, 0.0f); u1 = fmaxf(u1, 0.0f); u2 = fmaxf(u2, 0.0f);
        float d0 = sqrtf(u0), d1 = sqrtf(u1), d2 = sqrtf(u2);
        float w0 = 1.0f / fmaxf(d0, 1e-8f);
        float w1 = 1.0f / fmaxf(d1, 1e-8f);
        float w2 = 1.0f / fmaxf(d2, 1e-8f);
        float wsum = __fadd_rn(__fadd_rn(w0, w1), w2);
        w0 /= wsum; w1 /= wsum; w2 /= wsum;
        int nn = blockIdx.x * 64 + p;
        size_t base = ((size_t)b * NL + nn) * 3;
        idx[base] = j0; idx[base + 1] = j1; idx[base + 2] = j2;
        wgt[base] = w0; wgt[base + 1] = w1; wgt[base + 2] = w2;
    }
}

// ---------------------------------------------------------------------------
// feat_low (B, CL, NL) f32 -> Xb2[b][n][c] bf16, c in [0,128) (slim layout)
// ---------------------------------------------------------------------------
__global__ __launch_bounds__(256) void k_fl_t(const float* __restrict__ fl,
                                              unsigned short* __restrict__ Xb2) {
    __shared__ unsigned short s[32][68];
    int b = blockIdx.z, c0 = blockIdx.y * 32, n0 = blockIdx.x * 64;
    int tx = threadIdx.x & 63, ty = threadIdx.x >> 6;       // 64 x 4
    const float* src = fl + ((size_t)b * CL + c0) * NL + n0;
#pragma unroll
    for (int i = 0; i < 8; i++) {
        int c = ty * 8 + i;
        s[c][tx] = f2bf(src[(size_t)c * NL + tx]);
    }
    __syncthreads();
    int n = threadIdx.x >> 2, q = threadIdx.x & 3;
    ushort4b o0, o1;
#pragma unroll
    for (int e = 0; e < 4; e++) o0[e] = s[q * 8 + e][n];
#pragma unroll
    for (int e = 0; e < 4; e++) o1[e] = s[q * 8 + 4 + e][n];
    unsigned short* dst = Xb2 + ((size_t)b * NL + n0 + n) * CL + c0 + q * 8;
    *(ushort4b*)dst = o0;
    *(ushort4b*)(dst + 4) = o1;
}

// ---------------------------------------------------------------------------
// staging transforms
// ---------------------------------------------------------------------------
__device__ inline bfrag bnrelu8(bfrag v, f32x4 s0, f32x4 s1, f32x4 h0, f32x4 h1) {
    bfrag o;
#pragma unroll
    for (int e = 0; e < 4; e++)
        o[e] = (short)f2bf(fmaxf(fmaf(s0[e], bf2f((unsigned short)v[e]), h0[e]), 0.f));
#pragma unroll
    for (int e = 0; e < 4; e++)
        o[4 + e] = (short)f2bf(fmaxf(fmaf(s1[e], bf2f((unsigned short)v[4 + e]), h1[e]), 0.f));
    return o;
}

__device__ inline bfrag interp8(bfrag f0, bfrag f1, bfrag f2,
                                float w0, float w1, float w2) {
    bfrag o;
#pragma unroll
    for (int e = 0; e < 8; e++) {
        float f = __fadd_rn(__fadd_rn(__fmul_rn(w0, bf2f((unsigned short)f0[e])),
                                      __fmul_rn(w1, bf2f((unsigned short)f1[e]))),
                            __fmul_rn(w2, bf2f((unsigned short)f2[e])));
        o[e] = (short)f2bf(f);
    }
    return o;
}

// ---------------------------------------------------------------------------
// Fused MFMA GEMM: Y[b][n][m] = bf16( sum_k W[m][k]*X'[n][k] + bias[m] )
// BM=256 (all of M: X panel used once), BN=128, BK=32, 512 thr / 8 waves.
// INTERP: k<256 channels gathered+interpolated from fT on the fly (exact
//         __f*_rn chain == old k_interp); k>=256 read from slim Xb2[n][128].
// BN:     X' = relu(scale*X+shift) fused on staging (== old k_bn0 chain).
// Epilogue: per-block per-channel partial stats to distinct addresses.
// ---------------------------------------------------------------------------
__device__ inline int swz(int r, int cb) {
    return r * 32 + ((cb ^ ((r >> 1) & 3)) << 3);   // short index, 16B blocks
}

template <int K, bool INTERP, bool BN>
__global__ __launch_bounds__(512) void k_gemmf(const unsigned short* __restrict__ X,
                                               const unsigned short* __restrict__ fT,
                                               const int* __restrict__ idx,
                                               const float* __restrict__ wgt,
                                               const unsigned short* __restrict__ Wb,
                                               const float* __restrict__ bias,
                                               const float* __restrict__ bnsc,
                                               const float* __restrict__ bnsh,
                                               unsigned short* __restrict__ Y,
                                               float* __restrict__ psumT,
                                               float* __restrict__ psqT) {
    __shared__ __align__(16) unsigned short sA[2][256 * 32];   // 32 KB
    __shared__ __align__(16) unsigned short sB[2][128 * 32];   // 16 KB

    int bt = blockIdx.x;              // 0..511
    int xcd = bt & 7, ii = bt >> 3;   // ii: 0..63 within XCD
    int b  = xcd * 2 + (ii >> 5);     // 2 batches per XCD
    int n0 = (ii & 31) * 128;

    int tid = threadIdx.x;
    int lane = tid & 63;
    int wid = tid >> 6;               // 0..7
    int wm = wid >> 1, wn = wid & 1;  // 4 x 2 waves of 64x64

    int sr = tid >> 2;                // 0..127
    int scb = tid & 3;                // 16B block within BK row
    int swA0 = swz(sr, scb), swA1 = swz(sr + 128, scb);
    int swB = swz(sr, scb);

    const unsigned short* Wt = Wb + scb * 8;
    int nrow = n0 + sr;

    // per-thread interp metadata (hoisted once)
    const unsigned short* fTb;
    int ba0 = 0, ba1 = 0, ba2 = 0;
    float iw0 = 0.f, iw1 = 0.f, iw2 = 0.f;
    if (INTERP) {
        size_t ib = ((size_t)b * NL + nrow) * 3;
        ba0 = idx[ib] * CHH; ba1 = idx[ib + 1] * CHH; ba2 = idx[ib + 2] * CHH;
        iw0 = wgt[ib]; iw1 = wgt[ib + 1]; iw2 = wgt[ib + 2];
        fTb = fT + (size_t)b * NH * CHH;
    }
    const unsigned short* Xrow =
        X + ((size_t)b * NL + nrow) * (INTERP ? CL : CO);

    f32x4 acc[4][4] = {};

    // stage k-step tt into raw regs
    auto stageB = [&](int tt, bfrag& r0, bfrag& r1, bfrag& r2) {
        int cg = tt * 32 + scb * 8;
        if (INTERP) {
            if (cg < CHH) {
                r0 = *(const bfrag*)&fTb[ba0 + cg];
                r1 = *(const bfrag*)&fTb[ba1 + cg];
                r2 = *(const bfrag*)&fTb[ba2 + cg];
            } else {
                r0 = *(const bfrag*)&Xrow[cg - CHH];
            }
        } else {
            r0 = *(const bfrag*)&Xrow[cg];
        }
    };
    auto combineB = [&](int tt, bfrag r0, bfrag r1, bfrag r2) -> bfrag {
        int cg = tt * 32 + scb * 8;
        if (INTERP) {
            if (cg < CHH) return interp8(r0, r1, r2, iw0, iw1, iw2);
            return r0;
        }
        if (BN) {
            f32x4 sc0 = *(const f32x4*)&bnsc[cg], sc1 = *(const f32x4*)&bnsc[cg + 4];
            f32x4 sh0 = *(const f32x4*)&bnsh[cg], sh1 = *(const f32x4*)&bnsh[cg + 4];
            return bnrelu8(r0, sc0, sc1, sh0, sh1);
        }
        return r0;
    };

    // prologue: tile 0
    {
        bfrag a0 = *(const bfrag*)&Wt[(size_t)sr * K];
        bfrag a1 = *(const bfrag*)&Wt[(size_t)(sr + 128) * K];
        bfrag r0, r1, r2;
        stageB(0, r0, r1, r2);
        bfrag bb = combineB(0, r0, r1, r2);
        *(bfrag*)&sA[0][swA0] = a0;
        *(bfrag*)&sA[0][swA1] = a1;
        *(bfrag*)&sB[0][swB] = bb;
    }
    __syncthreads();

    const int nkt = K / 32;
    int cur = 0;
#pragma unroll 2
    for (int tt = 0; tt < nkt; tt++) {
        bfrag na0, na1, r0, r1, r2;
        bool more = (tt + 1 < nkt);
        if (more) {
            int kk = (tt + 1) * 32;
            na0 = *(const bfrag*)&Wt[(size_t)sr * K + kk];
            na1 = *(const bfrag*)&Wt[(size_t)(sr + 128) * K + kk];
            stageB(tt + 1, r0, r1, r2);
        }
        bfrag af[4], bf[4];
#pragma unroll
        for (int mi = 0; mi < 4; mi++) {
            int r = wm * 64 + mi * 16 + (lane & 15);
            af[mi] = *(const bfrag*)&sA[cur][swz(r, lane >> 4)];
        }
#pragma unroll
        for (int ni = 0; ni < 4; ni++) {
            int r = wn * 64 + ni * 16 + (lane & 15);
            bf[ni] = *(const bfrag*)&sB[cur][swz(r, lane >> 4)];
        }
#pragma unroll
        for (int mi = 0; mi < 4; mi++)
#pragma unroll
            for (int ni = 0; ni < 4; ni++)
                acc[mi][ni] = __builtin_amdgcn_mfma_f32_16x16x32_bf16(
                    af[mi], bf[ni], acc[mi][ni], 0, 0, 0);
        if (more) {
            bfrag nb = combineB(tt + 1, r0, r1, r2);
            *(bfrag*)&sA[cur ^ 1][swA0] = na0;
            *(bfrag*)&sA[cur ^ 1][swA1] = na1;
            *(bfrag*)&sB[cur ^ 1][swB] = nb;
            __syncthreads();
            cur ^= 1;
        }
    }

    // C frag: col = lane&15 (n), row = (lane>>4)*4 + j (m)
    int col = lane & 15, rg = (lane >> 4) << 2;
    int slot = bt * 2 + wn;
#pragma unroll
    for (int mi = 0; mi < 4; mi++) {
        int m = wm * 64 + mi * 16 + rg;
        f32x4 bv = *(const f32x4*)&bias[m];
        f32x4 sacc = {0.f, 0.f, 0.f, 0.f}, qacc = {0.f, 0.f, 0.f, 0.f};
#pragma unroll
        for (int ni = 0; ni < 4; ni++) {
            int n = n0 + wn * 64 + ni * 16 + col;
            f32x4 c = acc[mi][ni];
            ushort4b o;
#pragma unroll
            for (int j = 0; j < 4; j++) {
                float sv = c[j] + bv[j];
                o[j] = f2bf(sv);
                sacc[j] += sv;
                qacc[j] += sv * sv;
            }
            *(ushort4b*)&Y[((size_t)b * NL + n) * CO + m] = o;
        }
#pragma unroll
        for (int j = 0; j < 4; j++) {
            float s = sacc[j], q = qacc[j];
#pragma unroll
            for (int off = 1; off < 16; off <<= 1) {
                s += __shfl_xor(s, off, 64);
                q += __shfl_xor(q, off, 64);
            }
            if (col == 0) {
                psumT[(size_t)(m + j) * 1024 + slot] = s;
                psqT[(size_t)(m + j) * 1024 + slot] = q;
            }
        }
    }
}

// ---------------------------------------------------------------------------
// reduce per-block partials -> scale/shift. One block per channel.
// ---------------------------------------------------------------------------
__global__ __launch_bounds__(256) void k_fin(const float* __restrict__ psumT,
                                             const float* __restrict__ psqT,
                                             const float* __restrict__ gamma,
                                             const float* __restrict__ beta,
                                             float* __restrict__ scale,
                                             float* __restrict__ shift) {
    int c = blockIdx.x;
    const float* ps = psumT + (size_t)c * 1024;
    const float* pq = psqT + (size_t)c * 1024;
    float s = 0.f, q = 0.f;
    for (int i = threadIdx.x; i < 1024; i += 256) { s += ps[i]; q += pq[i]; }
#pragma unroll
    for (int off = 1; off < 64; off <<= 1) {
        s += __shfl_xor(s, off, 64);
        q += __shfl_xor(q, off, 64);
    }
    __shared__ float ls[4], lq[4];
    if ((threadIdx.x & 63) == 0) { ls[threadIdx.x >> 6] = s; lq[threadIdx.x >> 6] = q; }
    __syncthreads();
    if (threadIdx.x == 0) {
        float S = ls[0] + ls[1] + ls[2] + ls[3];
        float Q = lq[0] + lq[1] + lq[2] + lq[3];
        float N = (float)(BB * NL);
        float mean = S / N;
        float var = Q / N - mean * mean;
        float sc = gamma[c] / sqrtf(var + BN_EPS);
        scale[c] = sc;
        shift[c] = beta[c] - mean * sc;
    }
}

// ---------------------------------------------------------------------------
// final: read y1 bf16 [b][n][m], BN1+ReLU, transpose-write f32 out [b][m][n]
// ---------------------------------------------------------------------------
__global__ __launch_bounds__(256) void k_out(const unsigned short* __restrict__ y1,
                                             const float* __restrict__ scale,
                                             const float* __restrict__ shift,
                                             float* __restrict__ out) {
    __shared__ float s[64][65];
    int b = blockIdx.z, m0 = blockIdx.y * 64, n0 = blockIdx.x * 64;
    int r = threadIdx.x >> 3;            // 0..31
    int mq = (threadIdx.x & 7) * 8;      // 0..56
#pragma unroll
    for (int it = 0; it < 2; it++) {
        int row = r + it * 32;
        bfrag v = *(const bfrag*)&y1[((size_t)b * NL + n0 + row) * CO + m0 + mq];
#pragma unroll
        for (int e = 0; e < 8; e++) {
            int m = mq + e;
            float f = bf2f((unsigned short)v[e]);
            s[m][row] = fmaxf(fmaf(scale[m0 + m], f, shift[m0 + m]), 0.f);
        }
    }
    __syncthreads();
    int m = threadIdx.x >> 2, nb = (threadIdx.x & 3) * 16;
    float* orow = out + ((size_t)b * CO + m0 + m) * NL + n0 + nb;
#pragma unroll
    for (int i = 0; i < 16; i += 4) {
        float4 v = make_float4(s[m][nb + i], s[m][nb + i + 1],
                               s[m][nb + i + 2], s[m][nb + i + 3]);
        *(float4*)&orow[i] = v;
    }
}

// ---------------------------------------------------------------------------
extern "C" void kernel_launch(void* const* d_in, const int* in_sizes, int n_in,
                              void* d_out, int out_size, void* d_ws, size_t ws_size,
                              hipStream_t stream) {
    const float* xyz_low   = (const float*)d_in[0];
    const float* xyz_high  = (const float*)d_in[1];
    const float* feat_low  = (const float*)d_in[2];
    const float* feat_high = (const float*)d_in[3];
    const float* W0  = (const float*)d_in[4];
    const float* b0  = (const float*)d_in[5];
    const float* g0  = (const float*)d_in[6];
    const float* be0 = (const float*)d_in[7];
    const float* W1  = (const float*)d_in[8];
    const float* b1  = (const float*)d_in[9];
    const float* g1  = (const float*)d_in[10];
    const float* be1 = (const float*)d_in[11];
    float* out = (float*)d_out;

    char* ws = (char*)d_ws;
    // [Xb2 16MB][y0 32MB][y1 32MB (fT 8MB aliases start; dead before gemm1)]
    unsigned short* Xb2 = (unsigned short*)ws;
    unsigned short* y0  = (unsigned short*)(ws + ((size_t)16 << 20));
    unsigned short* y1  = (unsigned short*)(ws + ((size_t)48 << 20));
    unsigned short* fT  = (unsigned short*)(ws + ((size_t)48 << 20));
    char* tail          = ws + ((size_t)80 << 20);
    int*    idx   = (int*)tail;                       // 768 KB
    float*  wgt   = (float*)(tail + 786432);          // 768 KB
    float4* cand4 = (float4*)(tail + 2 * 786432);     // 256 KB
    unsigned short* Wb0 = (unsigned short*)(tail + 2 * 786432 + 262144);
    unsigned short* Wb1 = Wb0 + CO * K0;              // +192 KB
    char* tail2   = (char*)(Wb1 + CO * K1);           // +128 KB
    float* psumT0 = (float*)tail2;                    // 1 MB  [256][1024]
    float* psqT0  = psumT0 + 256 * 1024;              // 1 MB
    float* psumT1 = psqT0 + 256 * 1024;               // 1 MB
    float* psqT1  = psumT1 + 256 * 1024;              // 1 MB
    float* prm    = psqT1 + 256 * 1024;
    float* scale0 = prm,        *shift0 = prm + 256;
    float* scale1 = prm + 512,  *shift1 = prm + 768;

    k_setup<<<(CO * K0 + 255) / 256, 256, 0, stream>>>(W0, Wb0, W1, Wb1,
                                                       xyz_high, cand4);
    k_transpose_fh<<<dim3(NH / 32, CHH / 32, BB), 256, 0, stream>>>(feat_high, fT);
    k_knn<<<dim3(NL / 64, BB), 256, 0, stream>>>(xyz_low, cand4, idx, wgt);
    k_fl_t<<<dim3(NL / 64, CL / 32, BB), 256, 0, stream>>>(feat_low, Xb2);

    k_gemmf<K0, true, false><<<512, 512, 0, stream>>>(
        Xb2, fT, idx, wgt, Wb0, b0, nullptr, nullptr, y0, psumT0, psqT0);
    k_fin<<<256, 256, 0, stream>>>(psumT0, psqT0, g0, be0, scale0, shift0);
    k_gemmf<K1, false, true><<<512, 512, 0, stream>>>(
        y0, nullptr, nullptr, nullptr, Wb1, b1, scale0, shift0, y1, psumT1, psqT1);
    k_fin<<<256, 256, 0, stream>>>(psumT1, psqT1, g1, be1, scale1, shift1);
    k_out<<<dim3(NL / 64, CO / 64, BB), 256, 0, stream>>>(y1, scale1, shift1, out);
}